// Round 16
// baseline (224.056 us; speedup 1.0000x reference)
//
#include <hip/hip_runtime.h>
#include <cstddef>
#include <cstdint>

constexpr int BATCH = 64;
constexpr int CH    = 256;
constexpr int NPT   = 196;
constexpr int ROWS  = BATCH * NPT;   // 12544
constexpr int BSTRIDE = CH * NPT;    // 50176
constexpr int KNB   = 8;             // position 8 (9th) is never valid: k_int <= 8
constexpr int DSTR  = 208;           // D row stride (floats), 4 aligned 52-col quarters

typedef __bf16 bf16x8 __attribute__((ext_vector_type(8)));
typedef __bf16 bf16x4 __attribute__((ext_vector_type(4)));
typedef _Float16 f16x8 __attribute__((ext_vector_type(8)));
typedef float  f32x4  __attribute__((ext_vector_type(4)));
typedef unsigned long long u64;

__device__ __forceinline__ int src_batch(int b) {
    return (b & ~15) | ((b + 1) & 15);
}

__device__ __forceinline__ void gload_lds16(const void* g, void* l) {
    __builtin_amdgcn_global_load_lds(
        (const __attribute__((address_space(1))) void*)g,
        (__attribute__((address_space(3))) void*)l, 16, 0, 0);
}

// bijective XCD swizzle (m204): nwg must be %8==0
__device__ __forceinline__ int xcd_swz(int lin, int nwg) {
    int q = nwg >> 3;
    return (lin & 7) * q + (lin >> 3);
}

// ------- K1: trans_split+qs (0..1023) | KW compose (1024..1091) | W1catT (1092..1123) -------
__global__ __launch_bounds__(256) void front_kernel(const float* __restrict__ x,
        _Float16* __restrict__ XH, _Float16* __restrict__ XL,
        __bf16* __restrict__ XB, float* __restrict__ qsp,
        const float* __restrict__ fc1_w,
        const float* __restrict__ kp_w, const float* __restrict__ kp_b,
        const float* __restrict__ enc_w, const float* __restrict__ enc_b,
        const float* __restrict__ mu_w, const float* __restrict__ mu_b,
        const float* __restrict__ dec_w, const float* __restrict__ dec_b,
        __bf16* __restrict__ W1catT,
        float* __restrict__ KW1, float* __restrict__ kb1,
        float* __restrict__ KW2, float* __restrict__ kb2,
        int* __restrict__ smcnt) {
    __shared__ __attribute__((aligned(16))) char smem[16896];
    float (*tile)[65] = (float(*)[65])smem;
    int bid = blockIdx.x;
    int t = threadIdx.x;
    if (bid < 1024) {
        // ---- trans_split + qs quadrant partial ----
        int m0 = (bid & 3) * 64, c0 = ((bid >> 2) & 3) * 64, b = bid >> 4;
        const float* xb = x + (size_t)b * BSTRIDE;
        #pragma unroll
        for (int s = 0; s < 16; ++s) {
            int idx = s * 256 + t;
            int cc = idx >> 6, mm = idx & 63;
            int m = m0 + mm;
            float v = (m < NPT) ? xb[(size_t)(c0 + cc) * NPT + m] : 0.f;
            tile[cc][mm] = v;
            if (m < NPT)
                XB[(size_t)b * BSTRIDE + (size_t)(c0 + cc) * NPT + m] = (__bf16)v;
        }
        __syncthreads();
        #pragma unroll
        for (int s = 0; s < 16; ++s) {
            int idx = s * 256 + t;
            int mm = idx >> 6, cc = idx & 63;
            float v = tile[cc][mm];
            _Float16 h = (_Float16)v;
            size_t off = ((size_t)b * 256 + (m0 + mm)) * 256 + c0 + cc;
            XH[off] = h;
            XL[off] = (_Float16)(v - (float)h);
        }
        if (t < 64) {
            float acc = 0.f;
            #pragma unroll
            for (int cc = 0; cc < 64; ++cc) {
                float v = tile[cc][t];
                acc = fmaf(v, v, acc);
            }
            qsp[(size_t)(c0 >> 6) * 16384 + b * 256 + m0 + t] = acc;
        }
    } else if (bid < 1092) {
        // ---- k-predictor compose (f64, bit-identical) ----
        int pbid = bid - 1024;
        if (pbid == 0 && t == 0) smcnt[0] = 0;
        if (pbid < 64) {
            int i = pbid * 4 + (t >> 6);
            int j = t & 63;
            double acc = 0.0;
            for (int k = 0; k < 500; ++k)
                acc += (double)kp_w[(size_t)i * 500 + k] * (double)enc_w[(size_t)k * 64 + j];
            KW1[i * 64 + j] = (float)acc;
        } else if (pbid == 64) {
            int j = t;
            if (j < 64) {
                double acc = (double)enc_b[j];
                for (int k = 0; k < 500; ++k)
                    acc += (double)kp_b[k] * (double)enc_w[(size_t)k * 64 + j];
                kb1[j] = (float)acc;
            }
        } else {
            int e = (pbid - 65) * 256 + t;
            if (e < 576) {
                int i = e / 9, j = e - (e / 9) * 9;
                double acc = 0.0;
                for (int k = 0; k < 32; ++k)
                    acc += (double)mu_w[(size_t)i * 32 + k] * (double)dec_w[(size_t)k * 9 + j];
                KW2[e] = (float)acc;
            } else if (e < 585) {
                int j = e - 576;
                double acc = (double)dec_b[j];
                for (int k = 0; k < 32; ++k)
                    acc += (double)mu_b[k] * (double)dec_w[(size_t)k * 9 + j];
                kb2[j] = (float)acc;
            }
        }
    } else {
        // ---- W1catT transpose ([wa-wb | wb], bf16) ----
        int local = bid - 1092;                      // 0..31
        int n0 = (local >> 2) * 64, k0 = (local & 3) * 64;
        #pragma unroll
        for (int s = 0; s < 16; ++s) {
            int idx = s * 256 + t;
            int kk = idx >> 6, nn = idx & 63;
            float v;
            if (n0 < 256)
                v = fc1_w[(size_t)(k0 + kk) * 256 + n0 + nn] -
                    fc1_w[(size_t)(k0 + kk + 256) * 256 + n0 + nn];
            else
                v = fc1_w[(size_t)(k0 + kk + 256) * 256 + (n0 - 256) + nn];
            tile[kk][nn] = v;
        }
        __syncthreads();
        #pragma unroll
        for (int s = 0; s < 16; ++s) {
            int idx = s * 256 + t;
            int nn = idx >> 6, kk = idx & 63;
            W1catT[(size_t)(n0 + nn) * 256 + k0 + kk] = (__bf16)tile[kk][nn];
        }
    }
}

// ------- K2 mega-kernel: gram 64x64 dbuf BK=32 (0..2047) | k-predictor (2048..2831) -------
__global__ __launch_bounds__(256) void gram_kint(const _Float16* __restrict__ XH,
        const _Float16* __restrict__ XL, const float* __restrict__ qsp,
        float* __restrict__ Dw, const float* __restrict__ x,
        const float* __restrict__ W1, const float* __restrict__ b1,
        const float* __restrict__ W2, const float* __restrict__ b2,
        int* __restrict__ kint, float* __restrict__ degf) {
    __shared__ __attribute__((aligned(16))) char smem[32768];
    int bid = blockIdx.x;
    int t = threadIdx.x;
    if (bid < 2048) {
        int nid = xcd_swz(bid, 2048);
        int job = nid >> 4;
        int tile = nid & 15;
        int by = tile >> 2, bx = tile & 3;
        int r0 = by * 64, c0 = bx * 64;
        int qb = (job < 64) ? job : job - 64;
        int kb = (job < 64) ? qb : src_batch(qb);
        int w = t >> 6, l = t & 63;
        int lr = l & 15, lg = l >> 4;
        int wr = (w >> 1) * 32, wc = (w & 1) * 32;
        const _Float16* qh = XH + (size_t)qb * 65536;
        const _Float16* ql = XL + (size_t)qb * 65536;
        const _Float16* kh = XH + (size_t)kb * 65536;
        const _Float16* kl = XL + (size_t)kb * 65536;
        int srow = w * 16 + (l >> 2);
        int scb = (l & 3) * 8;
        f32x4 acc[2][2] = {};
        auto stage = [&](int k0, int bsel) {
            _Float16* base = (_Float16*)(smem + bsel * 16384);
            size_t goA = (size_t)(r0 + srow) * 256 + k0 + scb;
            size_t goB = (size_t)(c0 + srow) * 256 + k0 + scb;
            gload_lds16(qh + goA, base + w * 512);
            gload_lds16(ql + goA, base + 2048 + w * 512);
            gload_lds16(kh + goB, base + 4096 + w * 512);
            gload_lds16(kl + goB, base + 6144 + w * 512);
        };
        stage(0, 0);
        #pragma unroll
        for (int ks8 = 0; ks8 < 8; ++ks8) {
            if (ks8 < 7) {
                stage((ks8 + 1) * 32, (ks8 + 1) & 1);
                asm volatile("s_waitcnt vmcnt(4)" ::: "memory");
            } else {
                asm volatile("s_waitcnt vmcnt(0)" ::: "memory");
            }
            __syncthreads();
            _Float16* base = (_Float16*)(smem + (ks8 & 1) * 16384);
            _Float16* Ah = base;
            _Float16* Al = base + 2048;
            _Float16* Bh = base + 4096;
            _Float16* Bl = base + 6144;
            f16x8 ah[2], alv[2], bh[2], blv[2];
            #pragma unroll
            for (int mi = 0; mi < 2; ++mi) {
                ah[mi]  = *(const f16x8*)(Ah + (wr + mi * 16 + lr) * 32 + lg * 8);
                alv[mi] = *(const f16x8*)(Al + (wr + mi * 16 + lr) * 32 + lg * 8);
            }
            #pragma unroll
            for (int ni = 0; ni < 2; ++ni) {
                bh[ni]  = *(const f16x8*)(Bh + (wc + ni * 16 + lr) * 32 + lg * 8);
                blv[ni] = *(const f16x8*)(Bl + (wc + ni * 16 + lr) * 32 + lg * 8);
            }
            #pragma unroll
            for (int mi = 0; mi < 2; ++mi)
                #pragma unroll
                for (int ni = 0; ni < 2; ++ni) {
                    acc[mi][ni] = __builtin_amdgcn_mfma_f32_16x16x32_f16(
                        ah[mi], bh[ni], acc[mi][ni], 0, 0, 0);
                    acc[mi][ni] = __builtin_amdgcn_mfma_f32_16x16x32_f16(
                        ah[mi], blv[ni], acc[mi][ni], 0, 0, 0);
                    acc[mi][ni] = __builtin_amdgcn_mfma_f32_16x16x32_f16(
                        alv[mi], bh[ni], acc[mi][ni], 0, 0, 0);
                }
            __syncthreads();
        }
        float ksv[2];
        #pragma unroll
        for (int ni = 0; ni < 2; ++ni) {
            int col = c0 + wc + ni * 16 + lr;
            if (col < NPT) {
                size_t o0 = (size_t)kb * 256 + col;
                ksv[ni] = ((qsp[o0] + qsp[16384 + o0]) + qsp[32768 + o0]) +
                          qsp[49152 + o0];
            } else ksv[ni] = 0.f;
        }
        #pragma unroll
        for (int mi = 0; mi < 2; ++mi) {
            #pragma unroll
            for (int r = 0; r < 4; ++r) {
                if (r0 + wr + mi * 16 + r >= NPT) continue;  // wave-uniform skip
                int grow = r0 + wr + mi * 16 + lg * 4 + r;
                if (grow >= NPT) continue;
                size_t o0 = (size_t)qb * 256 + grow;
                float qq = ((qsp[o0] + qsp[16384 + o0]) + qsp[32768 + o0]) +
                           qsp[49152 + o0];
                size_t rbase = ((size_t)job * NPT + grow) * DSTR;
                #pragma unroll
                for (int ni = 0; ni < 2; ++ni) {
                    int col = c0 + wc + ni * 16 + lr;
                    if (col < NPT)
                        Dw[rbase + col] = qq - 2.f * acc[mi][ni][r] + ksv[ni];
                }
            }
        }
    } else {
        // ---- collapsed k-predictor ----
        float (*xr)[256] = (float(*)[256])smem;                  // 16384 B
        float (*ebuf)[64] = (float(*)[64])(smem + 16384);        //  4096 B
        float (*lg2)[9]  = (float(*)[9])(smem + 20480);          //   576 B
        int r0 = (bid - 2048) * 16;
        const float4* xg = (const float4*)(x + (size_t)r0 * 256);
        float4* xs = (float4*)&xr[0][0];
        #pragma unroll
        for (int s = 0; s < 4; ++s) xs[s * 256 + t] = xg[s * 256 + t];
        __syncthreads();
        int w = t >> 6, l = t & 63;
        {
            float bb = b1[l];
            float a0 = bb, a1 = bb, a2 = bb, a3 = bb;
            const float* x0 = xr[w * 4 + 0];
            const float* x1 = xr[w * 4 + 1];
            const float* x2 = xr[w * 4 + 2];
            const float* x3 = xr[w * 4 + 3];
            for (int c = 0; c < 256; ++c) {
                float wv = W1[c * 64 + l];
                a0 = fmaf(x0[c], wv, a0);
                a1 = fmaf(x1[c], wv, a1);
                a2 = fmaf(x2[c], wv, a2);
                a3 = fmaf(x3[c], wv, a3);
            }
            ebuf[w * 4 + 0][l] = fmaxf(a0, 0.f);
            ebuf[w * 4 + 1][l] = fmaxf(a1, 0.f);
            ebuf[w * 4 + 2][l] = fmaxf(a2, 0.f);
            ebuf[w * 4 + 3][l] = fmaxf(a3, 0.f);
        }
        __syncthreads();
        int rr = t >> 4, cc = t & 15;
        if (cc < 9) {
            float acc = b2[cc];
            for (int j = 0; j < 64; ++j)
                acc = fmaf(ebuf[rr][j], W2[j * 9 + cc], acc);
            lg2[rr][cc] = acc;
        }
        __syncthreads();
        if (cc == 0) {
            float best = lg2[rr][0];
            int bi = 0;
            #pragma unroll
            for (int j = 1; j < 9; ++j)
                if (lg2[rr][j] > best) { best = lg2[rr][j]; bi = j; }
            kint[r0 + rr] = bi;
            degf[r0 + rr] = (float)bi;
        }
    }
}

// ------- K3: topk (0..391) | P1 GEMM (392..783) | deferred prep (784..1425) -------
__global__ __launch_bounds__(256) void topk_p1(const float* __restrict__ Dw,
        int* __restrict__ nbr, const __bf16* __restrict__ XB,
        const __bf16* __restrict__ W1catT, __bf16* __restrict__ P1,
        const float* __restrict__ fc2_w, const float* __restrict__ fce_w,
        const float* __restrict__ upd_w, const float* __restrict__ inout_w,
        const float* __restrict__ inout_b, const float* __restrict__ upd_b,
        __bf16* __restrict__ W2catT, __bf16* __restrict__ fcet,
        __bf16* __restrict__ updC, float* __restrict__ bcomp) {
    __shared__ __attribute__((aligned(16))) char smem[32768];
    int bid = blockIdx.x;
    int t = threadIdx.x;
    if (bid < 392) {
        // ---- top-8: thread per (row, 52-col quarter) + in-block 4-way merge ----
        u64 (*lists)[4][8] = (u64(*)[4][8])smem;
        int lrow = t >> 2, q = t & 3;
        int rowid = bid * 64 + lrow;              // 392*64 = 25088 exactly
        const float* rp = Dw + (size_t)rowid * DSTR + q * 52;
        u64 kreg[8];
        #pragma unroll
        for (int p = 0; p < 8; ++p) kreg[p] = ~0ull;
        for (int s4 = 0; s4 < 13; ++s4) {
            f32x4 dv = *(const f32x4*)(rp + s4 * 4);
            #pragma unroll
            for (int e = 0; e < 4; ++e) {
                int col = q * 52 + s4 * 4 + e;
                unsigned u = __float_as_uint(dv[e]);
                u = (u & 0x80000000u) ? ~u : (u | 0x80000000u);
                u64 key = (col < NPT) ? (((u64)u << 32) | (unsigned)col) : ~0ull;
                if (key < kreg[7]) {
                    #pragma unroll
                    for (int p = 0; p < 8; ++p) {
                        u64 mn = (key < kreg[p]) ? key : kreg[p];
                        u64 mx = (key < kreg[p]) ? kreg[p] : key;
                        kreg[p] = mn; key = mx;
                    }
                }
            }
        }
        #pragma unroll
        for (int p = 0; p < 8; ++p) lists[lrow][q][p] = kreg[p];
        __syncthreads();
        if (q == 0) {
            const u64* c = &lists[lrow][0][0];
            int p0 = 0, p1 = 0, p2 = 0, p3 = 0;
            #pragma unroll
            for (int it = 0; it < 8; ++it) {
                u64 v0 = c[p0], v1 = c[8 + p1], v2 = c[16 + p2], v3 = c[24 + p3];
                u64 best = v0; int bj = 0;
                if (v1 < best) { best = v1; bj = 1; }
                if (v2 < best) { best = v2; bj = 2; }
                if (v3 < best) { best = v3; bj = 3; }
                if (bj == 0) p0 = (p0 < 7) ? p0 + 1 : 7;
                else if (bj == 1) p1 = (p1 < 7) ? p1 + 1 : 7;
                else if (bj == 2) p2 = (p2 < 7) ? p2 + 1 : 7;
                else p3 = (p3 < 7) ? p3 + 1 : 7;
                nbr[(size_t)rowid * KNB + it] = (int)(best & 0xffffffffu);
            }
        }
    } else if (bid < 784) {
        // ---- P1 projection: P1 = bf16(XB @ W1catT) ----
        __bf16* As = (__bf16*)smem;
        __bf16* Bs = As + 128 * 64;
        int lin = bid - 392;
        int nid = xcd_swz(lin, 392);
        int bx = nid & 3, by = nid >> 2;
        int w = t >> 6, l = t & 63;
        int r0 = by * 128, c0 = bx * 128;
        int lr = l & 15, lg = l >> 4;
        int wr = (w >> 1) * 64, wc = (w & 1) * 64;
        constexpr int K = 256, N = 512;
        f32x4 acc[4][4] = {};
        for (int k0 = 0; k0 < K; k0 += 64) {
            #pragma unroll
            for (int i = 0; i < 4; ++i) {
                int row = (w * 4 + i) * 8 + (l >> 3);
                int c8 = l & 7;
                gload_lds16(XB + (size_t)(r0 + row) * K + k0 + c8 * 8,
                            As + (w * 4 + i) * 512);
                gload_lds16(W1catT + (size_t)(c0 + row) * K + k0 + c8 * 8,
                            Bs + (w * 4 + i) * 512);
            }
            asm volatile("s_waitcnt vmcnt(0)" ::: "memory");
            __syncthreads();
            #pragma unroll
            for (int ks = 0; ks < 2; ++ks) {
                bf16x8 af[4], bfr[4];
                #pragma unroll
                for (int mi = 0; mi < 4; ++mi)
                    af[mi] = *(const bf16x8*)(As + (wr + mi * 16 + lr) * 64 + ks * 32 + lg * 8);
                #pragma unroll
                for (int ni = 0; ni < 4; ++ni)
                    bfr[ni] = *(const bf16x8*)(Bs + (wc + ni * 16 + lr) * 64 + ks * 32 + lg * 8);
                #pragma unroll
                for (int mi = 0; mi < 4; ++mi)
                    #pragma unroll
                    for (int ni = 0; ni < 4; ++ni)
                        acc[mi][ni] = __builtin_amdgcn_mfma_f32_16x16x32_bf16(
                            af[mi], bfr[ni], acc[mi][ni], 0, 0, 0);
            }
            __syncthreads();
        }
        #pragma unroll
        for (int mi = 0; mi < 4; ++mi) {
            #pragma unroll
            for (int r = 0; r < 4; ++r) {
                int row = r0 + wr + mi * 16 + lg * 4 + r;
                #pragma unroll
                for (int ni = 0; ni < 4; ++ni) {
                    int col = c0 + wc + ni * 16 + lr;
                    P1[(size_t)row * N + col] = (__bf16)acc[mi][ni][r];
                }
            }
        }
    } else if (bid < 816) {
        // ---- W2catT transpose ([wa-wb | wb], bf16) ----
        float (*tile)[65] = (float(*)[65])smem;
        int local = bid - 784;
        int n0 = (local >> 2) * 64, k0 = (local & 3) * 64;
        #pragma unroll
        for (int s = 0; s < 16; ++s) {
            int idx = s * 256 + t;
            int kk = idx >> 6, nn = idx & 63;
            float v;
            if (n0 < 256)
                v = fc2_w[(size_t)(k0 + kk) * 256 + n0 + nn] -
                    fc2_w[(size_t)(k0 + kk + 256) * 256 + n0 + nn];
            else
                v = fc2_w[(size_t)(k0 + kk + 256) * 256 + (n0 - 256) + nn];
            tile[kk][nn] = v;
        }
        __syncthreads();
        #pragma unroll
        for (int s = 0; s < 16; ++s) {
            int idx = s * 256 + t;
            int nn = idx >> 6, kk = idx & 63;
            W2catT[(size_t)(n0 + nn) * 256 + k0 + kk] = (__bf16)tile[kk][nn];
        }
    } else if (bid < 848) {
        // ---- fcet transpose ----
        float (*tile)[65] = (float(*)[65])smem;
        int local = bid - 816;
        int n0 = (local >> 2) * 64, k0 = (local & 3) * 64;
        #pragma unroll
        for (int s = 0; s < 16; ++s) {
            int idx = s * 256 + t;
            int kk = idx >> 6, nn = idx & 63;
            tile[kk][nn] = fce_w[(size_t)(k0 + kk) * 512 + n0 + nn];
        }
        __syncthreads();
        #pragma unroll
        for (int s = 0; s < 16; ++s) {
            int idx = s * 256 + t;
            int nn = idx >> 6, kk = idx & 63;
            fcet[(size_t)(n0 + nn) * 256 + k0 + kk] = (__bf16)tile[kk][nn];
        }
    } else if (bid < 912) {
        // ---- updC bottom half transpose (upd_w rows 512..1023) ----
        float (*tile)[65] = (float(*)[65])smem;
        int local = bid - 848;                       // 0..63
        int k0 = (local >> 3) * 64, n0 = (local & 7) * 64;
        #pragma unroll
        for (int s = 0; s < 16; ++s) {
            int idx = s * 256 + t;
            int kk = idx >> 6, nn = idx & 63;
            tile[kk][nn] = upd_w[(size_t)(512 + k0 + kk) * 512 + n0 + nn];
        }
        __syncthreads();
        #pragma unroll
        for (int s = 0; s < 16; ++s) {
            int idx = s * 256 + t;
            int nn = idx >> 6, kk = idx & 63;
            updC[(size_t)(n0 + nn) * 768 + 256 + k0 + kk] = (__bf16)tile[kk][nn];
        }
    } else if (bid < 1424) {
        // ---- updC compose (512 blocks, 1 output/thread, f64 bit-identical) ----
        int e = (bid - 912) * 256 + t;              // 0..131071
        int k = e >> 9, n = e & 511;
        double acc = 0.0;
        for (int j = 0; j < 512; ++j)
            acc += (double)inout_w[(size_t)k * 512 + j] * (double)upd_w[(size_t)j * 512 + n];
        updC[(size_t)n * 768 + k] = (__bf16)(float)acc;
    } else {
        // ---- bcomp ----
        int n = (bid - 1424) * 256 + t;              // 0..511
        double acc = (double)upd_b[n];
        for (int j = 0; j < 512; ++j)
            acc += (double)inout_b[j] * (double)upd_w[(size_t)j * 512 + n];
        bcomp[n] = (float)acc;
    }
}

// ------- combine: H[r] = (relu?)( deg*(Pa[self]+bias) + sum_nbr Pb ), XCD-swizzled -------
template<int STAGE, int RELU>
__global__ __launch_bounds__(256) void combine_kernel(const __bf16* __restrict__ P,
        const int* __restrict__ nbr, const int* __restrict__ kint_,
        const float* __restrict__ degf, const float* __restrict__ bias,
        __bf16* __restrict__ H) {
    int g = threadIdx.x >> 6, lane = threadIdx.x & 63;
    int nid = xcd_swz(blockIdx.x, 2 * ROWS / 4);
    int r = nid * 4 + g;                        // 0..2*ROWS
    int branch = (r >= ROWS);
    int rr = r - branch * ROWS;
    int b = rr / NPT, i = rr - b * NPT;
    size_t srow, mbase;
    if constexpr (STAGE == 1) {
        int fb = branch ? src_batch(b) : b;
        srow = (size_t)fb * NPT + i;
        mbase = (size_t)fb * NPT;
    } else {
        srow = (size_t)r;
        mbase = (size_t)branch * ROWS + (size_t)b * NPT;
    }
    const int* nb = nbr + (size_t)branch * ((size_t)ROWS * KNB) + (size_t)rr * KNB;
    bf16x4 sv = *(const bf16x4*)(P + srow * 512 + lane * 4);
    float4 bv = *(const float4*)(bias + lane * 4);
    float s0 = 0.f, s1 = 0.f, s2 = 0.f, s3 = 0.f;
    int kk = kint_[rr];
    for (int tt = 0; tt < kk; ++tt) {
        int m = nb[tt];
        bf16x4 v = *(const bf16x4*)(P + (mbase + m) * 512 + 256 + lane * 4);
        s0 += (float)v[0]; s1 += (float)v[1]; s2 += (float)v[2]; s3 += (float)v[3];
    }
    float dg = degf[rr];
    float o0 = fmaf(dg, (float)sv[0] + bv.x, s0);
    float o1 = fmaf(dg, (float)sv[1] + bv.y, s1);
    float o2 = fmaf(dg, (float)sv[2] + bv.z, s2);
    float o3 = fmaf(dg, (float)sv[3] + bv.w, s3);
    if constexpr (RELU) {
        o0 = fmaxf(o0, 0.f); o1 = fmaxf(o1, 0.f);
        o2 = fmaxf(o2, 0.f); o3 = fmaxf(o3, 0.f);
    }
    bf16x4 ov;
    ov[0] = (__bf16)o0; ov[1] = (__bf16)o1; ov[2] = (__bf16)o2; ov[3] = (__bf16)o3;
    *(bf16x4*)(H + (size_t)r * 256 + lane * 4) = ov;
}

// ---------------- bf16 MFMA GEMM (XCD-swizzled) ----------------
// FLAGS: 1=RELU, 4=bf16 out, 8=transposed out[b][c][i], 16=scores epilogue (implies bf16 out).
// CONCAT: 0 plain; 2 = A row = [A0(256) | wgt-mix of A1/A1+ROWS*512 (512)], K=768.
template<int FLAGS, int CONCAT>
__global__ __launch_bounds__(256) void mfma_gemm(
    const __bf16* __restrict__ A0, const __bf16* __restrict__ A1,
    const __bf16* __restrict__ WT, const float* __restrict__ bias,
    float* __restrict__ Cf, __bf16* __restrict__ Cb, int K, int N,
    const float* __restrict__ aw, float* __restrict__ scp,
    const float* __restrict__ wgt) {
    constexpr int SMEMB = (FLAGS & 8) ? (128 * 129 * 4) : (2 * 128 * 64 * 2);
    __shared__ __attribute__((aligned(16))) char smem[SMEMB];
    __bf16* As = (__bf16*)smem;
    __bf16* Bs = As + 128 * 64;
    int lin = blockIdx.x + 4 * blockIdx.y;
    int nid = xcd_swz(lin, 4 * gridDim.y);
    int bx = nid & 3, by = nid >> 2;
    int t = threadIdx.x, w = t >> 6, l = t & 63;
    int r0 = by * 128, c0 = bx * 128;
    int lr = l & 15, lg = l >> 4;
    int wr = (w >> 1) * 64, wc = (w & 1) * 64;
    f32x4 acc[4][4] = {};
    for (int k0 = 0; k0 < K; k0 += 64) {
        #pragma unroll
        for (int i = 0; i < 4; ++i) {
            int row = (w * 4 + i) * 8 + (l >> 3);
            int c8 = l & 7;
            if constexpr (CONCAT == 2) {
                if (k0 < 256) {
                    gload_lds16(A0 + (size_t)(r0 + row) * 256 + k0 + c8 * 8,
                                As + (w * 4 + i) * 512);
                } else {
                    int kk2 = k0 - 256 + c8 * 8;
                    size_t gr = (size_t)(r0 + row);
                    bf16x8 xa = *(const bf16x8*)(A1 + gr * 512 + kk2);
                    bf16x8 ya = *(const bf16x8*)(A1 + ((size_t)ROWS + gr) * 512 + kk2);
                    float wv = wgt[gr];
                    bf16x8 mx;
                    #pragma unroll
                    for (int j = 0; j < 8; ++j)
                        mx[j] = (__bf16)(wv * (float)xa[j] + (1.f - wv) * (float)ya[j]);
                    *(bf16x8*)(As + (w * 4 + i) * 512 + l * 8) = mx;
                }
            } else {
                gload_lds16(A0 + (size_t)(r0 + row) * K + k0 + c8 * 8,
                            As + (w * 4 + i) * 512);
            }
            gload_lds16(WT + (size_t)(c0 + row) * K + k0 + c8 * 8,
                        Bs + (w * 4 + i) * 512);
        }
        asm volatile("s_waitcnt vmcnt(0)" ::: "memory");
        __syncthreads();
        #pragma unroll
        for (int ks = 0; ks < 2; ++ks) {
            bf16x8 af[4], bfr[4];
            #pragma unroll
            for (int mi = 0; mi < 4; ++mi)
                af[mi] = *(const bf16x8*)(As + (wr + mi * 16 + lr) * 64 + ks * 32 + lg * 8);
            #pragma unroll
            for (int ni = 0; ni < 4; ++ni)
                bfr[ni] = *(const bf16x8*)(Bs + (wc + ni * 16 + lr) * 64 + ks * 32 + lg * 8);
            #pragma unroll
            for (int mi = 0; mi < 4; ++mi)
                #pragma unroll
                for (int ni = 0; ni < 4; ++ni)
                    acc[mi][ni] = __builtin_amdgcn_mfma_f32_16x16x32_bf16(
                        af[mi], bfr[ni], acc[mi][ni], 0, 0, 0);
        }
        __syncthreads();
    }
    if constexpr ((FLAGS & 8) != 0) {
        float* tile = (float*)smem;
        #pragma unroll
        for (int mi = 0; mi < 4; ++mi)
            #pragma unroll
            for (int r = 0; r < 4; ++r) {
                int rrow = wr + mi * 16 + lg * 4 + r;
                #pragma unroll
                for (int ni = 0; ni < 4; ++ni) {
                    int ccol = wc + ni * 16 + lr;
                    float v = acc[mi][ni][r];
                    if (bias) v += bias[c0 + ccol];
                    if constexpr ((FLAGS & 1) != 0) v = fmaxf(v, 0.f);
                    tile[rrow * 129 + ccol] = v;
                }
            }
        __syncthreads();
        int cc = t >> 6, rr2 = t & 63;
        #pragma unroll
        for (int cs = 0; cs < 128; cs += 4) {
            #pragma unroll
            for (int h = 0; h < 2; ++h) {
                int row = r0 + rr2 + h * 64;
                int bb = row / NPT, ii = row - bb * NPT;
                Cf[((size_t)bb * 512 + (c0 + cc + cs)) * NPT + ii] =
                    tile[(rr2 + h * 64) * 129 + cc + cs];
            }
        }
    } else if constexpr ((FLAGS & 16) != 0) {
        int half = (r0 >= ROWS) ? 1 : 0;
        float ps[4][4] = {};
        #pragma unroll
        for (int mi = 0; mi < 4; ++mi)
            #pragma unroll
            for (int r = 0; r < 4; ++r) {
                int row = r0 + wr + mi * 16 + lg * 4 + r;
                #pragma unroll
                for (int ni = 0; ni < 4; ++ni) {
                    int col = c0 + wc + ni * 16 + lr;
                    float v = acc[mi][ni][r] + bias[col];
                    Cb[(size_t)row * N + col] = (__bf16)v;
                    ps[mi][r] = fmaf(v, aw[half * 512 + col], ps[mi][r]);
                }
            }
        #pragma unroll
        for (int m = 1; m <= 8; m <<= 1)
            #pragma unroll
            for (int mi = 0; mi < 4; ++mi)
                #pragma unroll
                for (int r = 0; r < 4; ++r)
                    ps[mi][r] += __shfl_xor(ps[mi][r], m, 64);
        if (lr == 0) {
            int slot = half * 8 + bx * 2 + (w & 1);
            #pragma unroll
            for (int mi = 0; mi < 4; ++mi)
                #pragma unroll
                for (int r = 0; r < 4; ++r) {
                    int sr = r0 - half * ROWS + wr + mi * 16 + lg * 4 + r;
                    scp[(size_t)slot * ROWS + sr] = ps[mi][r];
                }
        }
    } else {
        #pragma unroll
        for (int mi = 0; mi < 4; ++mi) {
            #pragma unroll
            for (int r = 0; r < 4; ++r) {
                int row = r0 + wr + mi * 16 + lg * 4 + r;
                #pragma unroll
                for (int ni = 0; ni < 4; ++ni) {
                    int col = c0 + wc + ni * 16 + lr;
                    float v = acc[mi][ni][r];
                    if (bias) v += bias[col];
                    if constexpr ((FLAGS & 1) != 0) v = fmaxf(v, 0.f);
                    if constexpr ((FLAGS & 4) != 0)
                        Cb[(size_t)row * N + col] = (__bf16)v;
                    else
                        Cf[(size_t)row * N + col] = v;
                }
            }
        }
    }
}

// ------- single-dispatch softmax: per-block partials + fence/atomic last-block combine -------
__global__ __launch_bounds__(256) void softmax_all(const float* __restrict__ scp,
        const float* __restrict__ ab, float* __restrict__ scores,
        float* __restrict__ mpart, float* __restrict__ spart,
        int* __restrict__ cnt, float* __restrict__ wgt) {
    __shared__ float red[256];
    __shared__ float MS[2];
    __shared__ bool islast;
    int t = threadIdx.x;
    int sr = blockIdx.x * 256 + t;              // 49*256 = ROWS exactly
    float s = ab[0];
    #pragma unroll
    for (int i = 0; i < 16; ++i) s += scp[(size_t)i * ROWS + sr];
    scores[sr] = s;
    red[t] = s; __syncthreads();
    for (int off = 128; off; off >>= 1) {
        if (t < off) red[t] = fmaxf(red[t], red[t + off]);
        __syncthreads();
    }
    float mb = red[0]; __syncthreads();
    red[t] = expf(s - mb); __syncthreads();
    for (int off = 128; off; off >>= 1) {
        if (t < off) red[t] += red[t + off];
        __syncthreads();
    }
    if (t == 0) {
        mpart[blockIdx.x] = mb;
        spart[blockIdx.x] = red[0];
        __threadfence();
        int old = atomicAdd(cnt, 1);
        islast = (old == 48);
    }
    __syncthreads();
    if (!islast) return;
    __threadfence();
    if (t == 0) {
        float M = mpart[0];
        for (int i = 1; i < 49; ++i) M = fmaxf(M, mpart[i]);
        float S = 0.f;
        for (int i = 0; i < 49; ++i) S += spart[i] * expf(mpart[i] - M);
        MS[0] = M; MS[1] = S;
        cnt[0] = 0;
    }
    __syncthreads();
    float M = MS[0], denom = MS[1];
    for (int i = t; i < ROWS; i += 256)
        wgt[i] = expf(scores[i] - M) / denom;
}

extern "C" void kernel_launch(void* const* d_in, const int* in_sizes, int n_in,
                              void* d_out, int out_size, void* d_ws, size_t ws_size,
                              hipStream_t stream) {
    (void)in_sizes; (void)n_in; (void)out_size; (void)ws_size;
    const float* x       = (const float*)d_in[0];
    const float* fc1_w   = (const float*)d_in[1];
    const float* fc1_b   = (const float*)d_in[2];
    const float* fc2_w   = (const float*)d_in[3];
    const float* fc2_b   = (const float*)d_in[4];
    const float* fce_w   = (const float*)d_in[5];
    const float* fce_b   = (const float*)d_in[6];
    const float* inout_w = (const float*)d_in[7];
    const float* inout_b = (const float*)d_in[8];
    const float* attn_w  = (const float*)d_in[9];
    const float* attn_b  = (const float*)d_in[10];
    const float* upd_w   = (const float*)d_in[11];
    const float* upd_b   = (const float*)d_in[12];
    const float* kp_w    = (const float*)d_in[13];
    const float* kp_b    = (const float*)d_in[14];
    const float* enc_w   = (const float*)d_in[15];
    const float* enc_b   = (const float*)d_in[16];
    const float* mu_w    = (const float*)d_in[17];
    const float* mu_b    = (const float*)d_in[18];
    const float* dec_w   = (const float*)d_in[19];
    const float* dec_b   = (const float*)d_in[20];
    float* out = (float*)d_out;

    char* base = (char*)d_ws;
    size_t o = 0;
    auto alloc = [&](size_t bytes) -> void* {
        void* p = base + o;
        o += (bytes + 255) & ~(size_t)255;
        return p;
    };
    float* qsp    = (float*)alloc((size_t)4 * 64 * 256 * 4);        //  0.26 MB
    float* degf   = (float*)alloc(ROWS * 4);
    float* scores = (float*)alloc(ROWS * 4);
    float* wgt    = (float*)alloc(ROWS * 4);
    int*   kint   = (int*)  alloc(ROWS * 4);
    float* KW1    = (float*)alloc(256 * 64 * 4);
    float* kb1    = (float*)alloc(64 * 4);
    float* KW2    = (float*)alloc(64 * 9 * 4);
    float* kb2    = (float*)alloc(9 * 4);
    float* bcomp  = (float*)alloc(512 * 4);
    float* scp    = (float*)alloc((size_t)16 * ROWS * 4);           //  0.80 MB
    float* mpart  = (float*)alloc(64 * 4);
    float* spart  = (float*)alloc(64 * 4);
    int*   smcnt  = (int*)  alloc(256);
    int*   nbr    = (int*)  alloc((size_t)128 * NPT * KNB * 4);     //  0.80 MB
    char*  regD   = (char*) alloc((size_t)ROWS * 512 * 2);          // 12.85 MB
    __bf16* XB    = (__bf16*)alloc((size_t)ROWS * 256 * 2);         //  6.42 MB
    __bf16* H1    = (__bf16*)alloc((size_t)2 * ROWS * 256 * 2);     // 12.85 MB
    __bf16* H2    = (__bf16*)alloc((size_t)2 * ROWS * 256 * 2);     // 12.85 MB
    char*  regAGG = (char*) alloc((size_t)2 * ROWS * 512 * 4);      // 51.38 MB
    __bf16* W1catT= (__bf16*)alloc((size_t)512 * 256 * 2);
    __bf16* W2catT= (__bf16*)alloc((size_t)512 * 256 * 2);
    __bf16* fcet  = (__bf16*)alloc((size_t)512 * 256 * 2);
    __bf16* updC  = (__bf16*)alloc((size_t)512 * 768 * 2);
    // --- aliases (stream-order safe) ---
    __bf16* P1buf = (__bf16*)regD;                 // stage-1 P, dead after combine1
    _Float16* XSPH = (_Float16*)regAGG;            // [0, 8.39MB), dead after gram
    _Float16* XSPL = XSPH + (size_t)64 * 256 * 256;// [8.39, 16.78MB)
    float* Dw     = (float*)(regAGG + (size_t)17 * 1024 * 1024);  // 21.2MB, dead after topk
    __bf16* P2buf = (__bf16*)regAGG;               // stage-2 P (25.7MB), after topk
    __bf16* AGGb  = (__bf16*)regAGG;               // fce output (bf16), 25.7 MB
    __bf16* XAGGb = AGGb;

    // ---- K1: trans_split+qs + KW compose + W1catT (early-needed prep only) ----
    front_kernel<<<1124, 256, 0, stream>>>(x, XSPH, XSPL, XB, qsp,
                                           fc1_w, kp_w, kp_b, enc_w, enc_b,
                                           mu_w, mu_b, dec_w, dec_b,
                                           W1catT, KW1, kb1, KW2, kb2, smcnt);

    // ---- K2: gram 64x64 double-buffered (dist -> HBM) + collapsed k-predictor ----
    gram_kint<<<2832, 256, 0, stream>>>(XSPH, XSPL, qsp, Dw, x,
                                        KW1, kb1, KW2, kb2, kint, degf);

    // ---- K3: topk + P1 GEMM + deferred weight prep (late-needed) ----
    topk_p1<<<1426, 256, 0, stream>>>(Dw, nbr, XB, W1catT, P1buf,
                                      fc2_w, fce_w, upd_w, inout_w,
                                      inout_b, upd_b,
                                      W2catT, fcet, updC, bcomp);

    // ---- EdgeConv combine 1 ----
    combine_kernel<1, 1><<<2 * ROWS / 4, 256, 0, stream>>>(
        P1buf, nbr, kint, degf, fc1_b, H1);

    // ---- EdgeConv stage 2 ----
    mfma_gemm<4, 0><<<dim3(4, 196), 256, 0, stream>>>(
        H1, nullptr, W2catT, nullptr, nullptr, P2buf, 256, 512,
        nullptr, nullptr, nullptr);
    combine_kernel<2, 0><<<2 * ROWS / 4, 256, 0, stream>>>(
        P2buf, nbr, kint, degf, fc2_b, H2);

    // ---- fce (bf16 out + fused attention-score partials) ----
    mfma_gemm<20, 0><<<dim3(4, 196), 256, 0, stream>>>(
        H2, nullptr, fcet, fce_b, nullptr, AGGb, 256, 512,
        attn_w, scp, nullptr);

    // ---- softmax (single dispatch, deterministic last-block combine) ----
    softmax_all<<<49, 256, 0, stream>>>(scp, attn_b, scores, mpart, spart,
                                        smcnt, wgt);

    // ---- final upd GEMM: inline wgt-mix A-staging, composed inout, transposed out ----
    mfma_gemm<9, 2><<<dim3(4, 98), 256, 0, stream>>>(
        XB, XAGGb, updC, bcomp, out, nullptr, 768, 512,
        nullptr, nullptr, wgt);
}

// Round 17
// 211.196 us; speedup vs baseline: 1.0609x; 1.0609x over previous
//
#include <hip/hip_runtime.h>
#include <cstddef>
#include <cstdint>

constexpr int BATCH = 64;
constexpr int CH    = 256;
constexpr int NPT   = 196;
constexpr int ROWS  = BATCH * NPT;   // 12544
constexpr int BSTRIDE = CH * NPT;    // 50176
constexpr int KNB   = 8;             // position 8 (9th) is never valid: k_int <= 8
constexpr int DSTR  = 208;           // D row stride (floats), 4 aligned 52-col quarters

typedef __bf16 bf16x8 __attribute__((ext_vector_type(8)));
typedef __bf16 bf16x4 __attribute__((ext_vector_type(4)));
typedef _Float16 f16x8 __attribute__((ext_vector_type(8)));
typedef float  f32x4  __attribute__((ext_vector_type(4)));
typedef unsigned long long u64;

__device__ __forceinline__ int src_batch(int b) {
    return (b & ~15) | ((b + 1) & 15);
}

__device__ __forceinline__ void gload_lds16(const void* g, void* l) {
    __builtin_amdgcn_global_load_lds(
        (const __attribute__((address_space(1))) void*)g,
        (__attribute__((address_space(3))) void*)l, 16, 0, 0);
}

// bijective XCD swizzle (m204): nwg must be %8==0
__device__ __forceinline__ int xcd_swz(int lin, int nwg) {
    int q = nwg >> 3;
    return (lin & 7) * q + (lin >> 3);
}

// ------- K1: trans_split+qs (0..1023) | prep (1024..1765) -------
__global__ __launch_bounds__(256) void front_kernel(const float* __restrict__ x,
        _Float16* __restrict__ XH, _Float16* __restrict__ XL,
        __bf16* __restrict__ XB, float* __restrict__ qsp,
        const float* __restrict__ fc1_w, const float* __restrict__ fc2_w,
        const float* __restrict__ fce_w, const float* __restrict__ upd_w,
        const float* __restrict__ kp_w, const float* __restrict__ kp_b,
        const float* __restrict__ enc_w, const float* __restrict__ enc_b,
        const float* __restrict__ mu_w, const float* __restrict__ mu_b,
        const float* __restrict__ dec_w, const float* __restrict__ dec_b,
        const float* __restrict__ inout_w, const float* __restrict__ inout_b,
        const float* __restrict__ upd_b,
        __bf16* __restrict__ W1catT, __bf16* __restrict__ W2catT,
        __bf16* __restrict__ fcet, __bf16* __restrict__ updC,
        float* __restrict__ KW1, float* __restrict__ kb1,
        float* __restrict__ KW2, float* __restrict__ kb2,
        float* __restrict__ bcomp, int* __restrict__ smcnt) {
    __shared__ __attribute__((aligned(16))) char smem[16896];
    float (*tile)[65] = (float(*)[65])smem;
    int bid = blockIdx.x;
    int t = threadIdx.x;
    if (bid < 1024) {
        // ---- trans_split + qs quadrant partial ----
        int m0 = (bid & 3) * 64, c0 = ((bid >> 2) & 3) * 64, b = bid >> 4;
        const float* xb = x + (size_t)b * BSTRIDE;
        #pragma unroll
        for (int s = 0; s < 16; ++s) {
            int idx = s * 256 + t;
            int cc = idx >> 6, mm = idx & 63;
            int m = m0 + mm;
            float v = (m < NPT) ? xb[(size_t)(c0 + cc) * NPT + m] : 0.f;
            tile[cc][mm] = v;
            if (m < NPT)
                XB[(size_t)b * BSTRIDE + (size_t)(c0 + cc) * NPT + m] = (__bf16)v;
        }
        __syncthreads();
        #pragma unroll
        for (int s = 0; s < 16; ++s) {
            int idx = s * 256 + t;
            int mm = idx >> 6, cc = idx & 63;
            float v = tile[cc][mm];
            _Float16 h = (_Float16)v;
            size_t off = ((size_t)b * 256 + (m0 + mm)) * 256 + c0 + cc;
            XH[off] = h;
            XL[off] = (_Float16)(v - (float)h);
        }
        if (t < 64) {
            float acc = 0.f;
            #pragma unroll
            for (int cc = 0; cc < 64; ++cc) {
                float v = tile[cc][t];
                acc = fmaf(v, v, acc);
            }
            qsp[(size_t)(c0 >> 6) * 16384 + b * 256 + m0 + t] = acc;
        }
    } else {
        // ---- prep (weight transposes + compositions) ----
        int pbid = bid - 1024;
        if (pbid == 0 && t == 0) smcnt[0] = 0;   // reset softmax counter each call
        if (pbid < 64) {
            const float* W = (pbid < 32) ? fc1_w : fc2_w;
            __bf16* WT = (pbid < 32) ? W1catT : W2catT;
            int local = pbid & 31;
            int n0 = (local >> 2) * 64, k0 = (local & 3) * 64;
            #pragma unroll
            for (int s = 0; s < 16; ++s) {
                int idx = s * 256 + t;
                int kk = idx >> 6, nn = idx & 63;
                float v;
                if (n0 < 256)
                    v = W[(size_t)(k0 + kk) * 256 + n0 + nn] -
                        W[(size_t)(k0 + kk + 256) * 256 + n0 + nn];
                else
                    v = W[(size_t)(k0 + kk + 256) * 256 + (n0 - 256) + nn];
                tile[kk][nn] = v;
            }
            __syncthreads();
            #pragma unroll
            for (int s = 0; s < 16; ++s) {
                int idx = s * 256 + t;
                int nn = idx >> 6, kk = idx & 63;
                WT[(size_t)(n0 + nn) * 256 + k0 + kk] = (__bf16)tile[kk][nn];
            }
        } else if (pbid < 96) {
            int local = pbid - 64;
            int n0 = (local >> 2) * 64, k0 = (local & 3) * 64;
            #pragma unroll
            for (int s = 0; s < 16; ++s) {
                int idx = s * 256 + t;
                int kk = idx >> 6, nn = idx & 63;
                tile[kk][nn] = fce_w[(size_t)(k0 + kk) * 512 + n0 + nn];
            }
            __syncthreads();
            #pragma unroll
            for (int s = 0; s < 16; ++s) {
                int idx = s * 256 + t;
                int nn = idx >> 6, kk = idx & 63;
                fcet[(size_t)(n0 + nn) * 256 + k0 + kk] = (__bf16)tile[kk][nn];
            }
        } else if (pbid < 160) {
            int local = pbid - 96;                       // 0..63
            int k0 = (local >> 3) * 64, n0 = (local & 7) * 64;
            #pragma unroll
            for (int s = 0; s < 16; ++s) {
                int idx = s * 256 + t;
                int kk = idx >> 6, nn = idx & 63;
                tile[kk][nn] = upd_w[(size_t)(512 + k0 + kk) * 512 + n0 + nn];
            }
            __syncthreads();
            #pragma unroll
            for (int s = 0; s < 16; ++s) {
                int idx = s * 256 + t;
                int nn = idx >> 6, kk = idx & 63;
                updC[(size_t)(n0 + nn) * 768 + 256 + k0 + kk] = (__bf16)tile[kk][nn];
            }
        } else if (pbid < 224) {
            // KW1 compose stays f64 (argmax-sensitive)
            int i = (pbid - 160) * 4 + (t >> 6);
            int j = t & 63;
            double acc = 0.0;
            for (int k = 0; k < 500; ++k)
                acc += (double)kp_w[(size_t)i * 500 + k] * (double)enc_w[(size_t)k * 64 + j];
            KW1[i * 64 + j] = (float)acc;
        } else if (pbid == 224) {
            int j = t;
            if (j < 64) {
                double acc = (double)enc_b[j];
                for (int k = 0; k < 500; ++k)
                    acc += (double)kp_b[k] * (double)enc_w[(size_t)k * 64 + j];
                kb1[j] = (float)acc;
            }
        } else if (pbid < 228) {
            int e = (pbid - 225) * 256 + t;
            if (e < 576) {
                int i = e / 9, j = e - (e / 9) * 9;
                double acc = 0.0;
                for (int k = 0; k < 32; ++k)
                    acc += (double)mu_w[(size_t)i * 32 + k] * (double)dec_w[(size_t)k * 9 + j];
                KW2[e] = (float)acc;
            } else if (e < 585) {
                int j = e - 576;
                double acc = (double)dec_b[j];
                for (int k = 0; k < 32; ++k)
                    acc += (double)mu_b[k] * (double)dec_w[(size_t)k * 9 + j];
                kb2[j] = (float)acc;
            }
        } else if (pbid < 740) {
            // updC compose: f32, 4 split accumulators (output is bf16 — f64 overkill)
            int e = (pbid - 228) * 256 + t;              // 0..131071
            int k = e >> 9, n = e & 511;
            const float* iw = inout_w + (size_t)k * 512;
            float a0 = 0.f, a1 = 0.f, a2 = 0.f, a3 = 0.f;
            for (int j = 0; j < 512; j += 4) {
                a0 = fmaf(iw[j + 0], upd_w[(size_t)(j + 0) * 512 + n], a0);
                a1 = fmaf(iw[j + 1], upd_w[(size_t)(j + 1) * 512 + n], a1);
                a2 = fmaf(iw[j + 2], upd_w[(size_t)(j + 2) * 512 + n], a2);
                a3 = fmaf(iw[j + 3], upd_w[(size_t)(j + 3) * 512 + n], a3);
            }
            updC[(size_t)n * 768 + k] = (__bf16)((a0 + a1) + (a2 + a3));
        } else {
            // bcomp: f32, 4 split accumulators (feeds f32 bias add — tolerant)
            int n = (pbid - 740) * 256 + t;              // 0..511
            float a0 = upd_b[n], a1 = 0.f, a2 = 0.f, a3 = 0.f;
            for (int j = 0; j < 512; j += 4) {
                a0 = fmaf(inout_b[j + 0], upd_w[(size_t)(j + 0) * 512 + n], a0);
                a1 = fmaf(inout_b[j + 1], upd_w[(size_t)(j + 1) * 512 + n], a1);
                a2 = fmaf(inout_b[j + 2], upd_w[(size_t)(j + 2) * 512 + n], a2);
                a3 = fmaf(inout_b[j + 3], upd_w[(size_t)(j + 3) * 512 + n], a3);
            }
            bcomp[n] = (a0 + a1) + (a2 + a3);
        }
    }
}

// ------- K2 mega-kernel: gram 64x64 dbuf BK=32 (0..2047) | k-predictor (2048..2831) -------
__global__ __launch_bounds__(256) void gram_kint(const _Float16* __restrict__ XH,
        const _Float16* __restrict__ XL, const float* __restrict__ qsp,
        float* __restrict__ Dw, const float* __restrict__ x,
        const float* __restrict__ W1, const float* __restrict__ b1,
        const float* __restrict__ W2, const float* __restrict__ b2,
        int* __restrict__ kint, float* __restrict__ degf) {
    __shared__ __attribute__((aligned(16))) char smem[32768];
    int bid = blockIdx.x;
    int t = threadIdx.x;
    if (bid < 2048) {
        int nid = xcd_swz(bid, 2048);
        int job = nid >> 4;
        int tile = nid & 15;
        int by = tile >> 2, bx = tile & 3;
        int r0 = by * 64, c0 = bx * 64;
        int qb = (job < 64) ? job : job - 64;
        int kb = (job < 64) ? qb : src_batch(qb);
        int w = t >> 6, l = t & 63;
        int lr = l & 15, lg = l >> 4;
        int wr = (w >> 1) * 32, wc = (w & 1) * 32;
        const _Float16* qh = XH + (size_t)qb * 65536;
        const _Float16* ql = XL + (size_t)qb * 65536;
        const _Float16* kh = XH + (size_t)kb * 65536;
        const _Float16* kl = XL + (size_t)kb * 65536;
        int srow = w * 16 + (l >> 2);
        int scb = (l & 3) * 8;
        f32x4 acc[2][2] = {};
        auto stage = [&](int k0, int bsel) {
            _Float16* base = (_Float16*)(smem + bsel * 16384);
            size_t goA = (size_t)(r0 + srow) * 256 + k0 + scb;
            size_t goB = (size_t)(c0 + srow) * 256 + k0 + scb;
            gload_lds16(qh + goA, base + w * 512);
            gload_lds16(ql + goA, base + 2048 + w * 512);
            gload_lds16(kh + goB, base + 4096 + w * 512);
            gload_lds16(kl + goB, base + 6144 + w * 512);
        };
        stage(0, 0);
        #pragma unroll
        for (int ks8 = 0; ks8 < 8; ++ks8) {
            if (ks8 < 7) {
                stage((ks8 + 1) * 32, (ks8 + 1) & 1);
                asm volatile("s_waitcnt vmcnt(4)" ::: "memory");
            } else {
                asm volatile("s_waitcnt vmcnt(0)" ::: "memory");
            }
            __syncthreads();
            _Float16* base = (_Float16*)(smem + (ks8 & 1) * 16384);
            _Float16* Ah = base;
            _Float16* Al = base + 2048;
            _Float16* Bh = base + 4096;
            _Float16* Bl = base + 6144;
            f16x8 ah[2], alv[2], bh[2], blv[2];
            #pragma unroll
            for (int mi = 0; mi < 2; ++mi) {
                ah[mi]  = *(const f16x8*)(Ah + (wr + mi * 16 + lr) * 32 + lg * 8);
                alv[mi] = *(const f16x8*)(Al + (wr + mi * 16 + lr) * 32 + lg * 8);
            }
            #pragma unroll
            for (int ni = 0; ni < 2; ++ni) {
                bh[ni]  = *(const f16x8*)(Bh + (wc + ni * 16 + lr) * 32 + lg * 8);
                blv[ni] = *(const f16x8*)(Bl + (wc + ni * 16 + lr) * 32 + lg * 8);
            }
            #pragma unroll
            for (int mi = 0; mi < 2; ++mi)
                #pragma unroll
                for (int ni = 0; ni < 2; ++ni) {
                    acc[mi][ni] = __builtin_amdgcn_mfma_f32_16x16x32_f16(
                        ah[mi], bh[ni], acc[mi][ni], 0, 0, 0);
                    acc[mi][ni] = __builtin_amdgcn_mfma_f32_16x16x32_f16(
                        ah[mi], blv[ni], acc[mi][ni], 0, 0, 0);
                    acc[mi][ni] = __builtin_amdgcn_mfma_f32_16x16x32_f16(
                        alv[mi], bh[ni], acc[mi][ni], 0, 0, 0);
                }
            __syncthreads();
        }
        float ksv[2];
        #pragma unroll
        for (int ni = 0; ni < 2; ++ni) {
            int col = c0 + wc + ni * 16 + lr;
            if (col < NPT) {
                size_t o0 = (size_t)kb * 256 + col;
                ksv[ni] = ((qsp[o0] + qsp[16384 + o0]) + qsp[32768 + o0]) +
                          qsp[49152 + o0];
            } else ksv[ni] = 0.f;
        }
        #pragma unroll
        for (int mi = 0; mi < 2; ++mi) {
            #pragma unroll
            for (int r = 0; r < 4; ++r) {
                if (r0 + wr + mi * 16 + r >= NPT) continue;  // wave-uniform skip
                int grow = r0 + wr + mi * 16 + lg * 4 + r;
                if (grow >= NPT) continue;
                size_t o0 = (size_t)qb * 256 + grow;
                float qq = ((qsp[o0] + qsp[16384 + o0]) + qsp[32768 + o0]) +
                           qsp[49152 + o0];
                size_t rbase = ((size_t)job * NPT + grow) * DSTR;
                #pragma unroll
                for (int ni = 0; ni < 2; ++ni) {
                    int col = c0 + wc + ni * 16 + lr;
                    if (col < NPT)
                        Dw[rbase + col] = qq - 2.f * acc[mi][ni][r] + ksv[ni];
                }
            }
        }
    } else {
        // ---- collapsed k-predictor ----
        float (*xr)[256] = (float(*)[256])smem;                  // 16384 B
        float (*ebuf)[64] = (float(*)[64])(smem + 16384);        //  4096 B
        float (*lg2)[9]  = (float(*)[9])(smem + 20480);          //   576 B
        int r0 = (bid - 2048) * 16;
        const float4* xg = (const float4*)(x + (size_t)r0 * 256);
        float4* xs = (float4*)&xr[0][0];
        #pragma unroll
        for (int s = 0; s < 4; ++s) xs[s * 256 + t] = xg[s * 256 + t];
        __syncthreads();
        int w = t >> 6, l = t & 63;
        {
            float bb = b1[l];
            float a0 = bb, a1 = bb, a2 = bb, a3 = bb;
            const float* x0 = xr[w * 4 + 0];
            const float* x1 = xr[w * 4 + 1];
            const float* x2 = xr[w * 4 + 2];
            const float* x3 = xr[w * 4 + 3];
            for (int c = 0; c < 256; ++c) {
                float wv = W1[c * 64 + l];
                a0 = fmaf(x0[c], wv, a0);
                a1 = fmaf(x1[c], wv, a1);
                a2 = fmaf(x2[c], wv, a2);
                a3 = fmaf(x3[c], wv, a3);
            }
            ebuf[w * 4 + 0][l] = fmaxf(a0, 0.f);
            ebuf[w * 4 + 1][l] = fmaxf(a1, 0.f);
            ebuf[w * 4 + 2][l] = fmaxf(a2, 0.f);
            ebuf[w * 4 + 3][l] = fmaxf(a3, 0.f);
        }
        __syncthreads();
        int rr = t >> 4, cc = t & 15;
        if (cc < 9) {
            float acc = b2[cc];
            for (int j = 0; j < 64; ++j)
                acc = fmaf(ebuf[rr][j], W2[j * 9 + cc], acc);
            lg2[rr][cc] = acc;
        }
        __syncthreads();
        if (cc == 0) {
            float best = lg2[rr][0];
            int bi = 0;
            #pragma unroll
            for (int j = 1; j < 9; ++j)
                if (lg2[rr][j] > best) { best = lg2[rr][j]; bi = j; }
            kint[r0 + rr] = bi;
            degf[r0 + rr] = (float)bi;
        }
    }
}

// ------- K3: topk (0..391) | P1 projection GEMM (392..783) -------
__global__ __launch_bounds__(256) void topk_p1(const float* __restrict__ Dw,
        int* __restrict__ nbr, const __bf16* __restrict__ XB,
        const __bf16* __restrict__ W1catT, __bf16* __restrict__ P1) {
    __shared__ __attribute__((aligned(16))) char smem[32768];
    int bid = blockIdx.x;
    int t = threadIdx.x;
    if (bid < 392) {
        // ---- top-8: thread per (row, 52-col quarter) + in-block 4-way merge ----
        u64 (*lists)[4][8] = (u64(*)[4][8])smem;
        int lrow = t >> 2, q = t & 3;
        int rowid = bid * 64 + lrow;              // 392*64 = 25088 exactly
        const float* rp = Dw + (size_t)rowid * DSTR + q * 52;
        u64 kreg[8];
        #pragma unroll
        for (int p = 0; p < 8; ++p) kreg[p] = ~0ull;
        for (int s4 = 0; s4 < 13; ++s4) {
            f32x4 dv = *(const f32x4*)(rp + s4 * 4);
            #pragma unroll
            for (int e = 0; e < 4; ++e) {
                int col = q * 52 + s4 * 4 + e;
                unsigned u = __float_as_uint(dv[e]);
                u = (u & 0x80000000u) ? ~u : (u | 0x80000000u);
                u64 key = (col < NPT) ? (((u64)u << 32) | (unsigned)col) : ~0ull;
                if (key < kreg[7]) {
                    #pragma unroll
                    for (int p = 0; p < 8; ++p) {
                        u64 mn = (key < kreg[p]) ? key : kreg[p];
                        u64 mx = (key < kreg[p]) ? kreg[p] : key;
                        kreg[p] = mn; key = mx;
                    }
                }
            }
        }
        #pragma unroll
        for (int p = 0; p < 8; ++p) lists[lrow][q][p] = kreg[p];
        __syncthreads();
        if (q == 0) {
            const u64* c = &lists[lrow][0][0];
            int p0 = 0, p1 = 0, p2 = 0, p3 = 0;
            #pragma unroll
            for (int it = 0; it < 8; ++it) {
                u64 v0 = c[p0], v1 = c[8 + p1], v2 = c[16 + p2], v3 = c[24 + p3];
                u64 best = v0; int bj = 0;
                if (v1 < best) { best = v1; bj = 1; }
                if (v2 < best) { best = v2; bj = 2; }
                if (v3 < best) { best = v3; bj = 3; }
                if (bj == 0) p0 = (p0 < 7) ? p0 + 1 : 7;
                else if (bj == 1) p1 = (p1 < 7) ? p1 + 1 : 7;
                else if (bj == 2) p2 = (p2 < 7) ? p2 + 1 : 7;
                else p3 = (p3 < 7) ? p3 + 1 : 7;
                nbr[(size_t)rowid * KNB + it] = (int)(best & 0xffffffffu);
            }
        }
    } else {
        // ---- P1 projection: P1 = bf16(XB @ W1catT) ----
        __bf16* As = (__bf16*)smem;
        __bf16* Bs = As + 128 * 64;
        int lin = bid - 392;
        int nid = xcd_swz(lin, 392);
        int bx = nid & 3, by = nid >> 2;
        int w = t >> 6, l = t & 63;
        int r0 = by * 128, c0 = bx * 128;
        int lr = l & 15, lg = l >> 4;
        int wr = (w >> 1) * 64, wc = (w & 1) * 64;
        constexpr int K = 256, N = 512;
        f32x4 acc[4][4] = {};
        for (int k0 = 0; k0 < K; k0 += 64) {
            #pragma unroll
            for (int i = 0; i < 4; ++i) {
                int row = (w * 4 + i) * 8 + (l >> 3);
                int c8 = l & 7;
                gload_lds16(XB + (size_t)(r0 + row) * K + k0 + c8 * 8,
                            As + (w * 4 + i) * 512);
                gload_lds16(W1catT + (size_t)(c0 + row) * K + k0 + c8 * 8,
                            Bs + (w * 4 + i) * 512);
            }
            asm volatile("s_waitcnt vmcnt(0)" ::: "memory");
            __syncthreads();
            #pragma unroll
            for (int ks = 0; ks < 2; ++ks) {
                bf16x8 af[4], bfr[4];
                #pragma unroll
                for (int mi = 0; mi < 4; ++mi)
                    af[mi] = *(const bf16x8*)(As + (wr + mi * 16 + lr) * 64 + ks * 32 + lg * 8);
                #pragma unroll
                for (int ni = 0; ni < 4; ++ni)
                    bfr[ni] = *(const bf16x8*)(Bs + (wc + ni * 16 + lr) * 64 + ks * 32 + lg * 8);
                #pragma unroll
                for (int mi = 0; mi < 4; ++mi)
                    #pragma unroll
                    for (int ni = 0; ni < 4; ++ni)
                        acc[mi][ni] = __builtin_amdgcn_mfma_f32_16x16x32_bf16(
                            af[mi], bfr[ni], acc[mi][ni], 0, 0, 0);
            }
            __syncthreads();
        }
        #pragma unroll
        for (int mi = 0; mi < 4; ++mi) {
            #pragma unroll
            for (int r = 0; r < 4; ++r) {
                int row = r0 + wr + mi * 16 + lg * 4 + r;
                #pragma unroll
                for (int ni = 0; ni < 4; ++ni) {
                    int col = c0 + wc + ni * 16 + lr;
                    P1[(size_t)row * N + col] = (__bf16)acc[mi][ni][r];
                }
            }
        }
    }
}

// ------- combine: H[r] = (relu?)( deg*(Pa[self]+bias) + sum_nbr Pb ), XCD-swizzled -------
template<int STAGE, int RELU>
__global__ __launch_bounds__(256) void combine_kernel(const __bf16* __restrict__ P,
        const int* __restrict__ nbr, const int* __restrict__ kint_,
        const float* __restrict__ degf, const float* __restrict__ bias,
        __bf16* __restrict__ H) {
    int g = threadIdx.x >> 6, lane = threadIdx.x & 63;
    int nid = xcd_swz(blockIdx.x, 2 * ROWS / 4);
    int r = nid * 4 + g;                        // 0..2*ROWS
    int branch = (r >= ROWS);
    int rr = r - branch * ROWS;
    int b = rr / NPT, i = rr - b * NPT;
    size_t srow, mbase;
    if constexpr (STAGE == 1) {
        int fb = branch ? src_batch(b) : b;
        srow = (size_t)fb * NPT + i;
        mbase = (size_t)fb * NPT;
    } else {
        srow = (size_t)r;
        mbase = (size_t)branch * ROWS + (size_t)b * NPT;
    }
    const int* nb = nbr + (size_t)branch * ((size_t)ROWS * KNB) + (size_t)rr * KNB;
    bf16x4 sv = *(const bf16x4*)(P + srow * 512 + lane * 4);
    float4 bv = *(const float4*)(bias + lane * 4);
    float s0 = 0.f, s1 = 0.f, s2 = 0.f, s3 = 0.f;
    int kk = kint_[rr];
    for (int tt = 0; tt < kk; ++tt) {
        int m = nb[tt];
        bf16x4 v = *(const bf16x4*)(P + (mbase + m) * 512 + 256 + lane * 4);
        s0 += (float)v[0]; s1 += (float)v[1]; s2 += (float)v[2]; s3 += (float)v[3];
    }
    float dg = degf[rr];
    float o0 = fmaf(dg, (float)sv[0] + bv.x, s0);
    float o1 = fmaf(dg, (float)sv[1] + bv.y, s1);
    float o2 = fmaf(dg, (float)sv[2] + bv.z, s2);
    float o3 = fmaf(dg, (float)sv[3] + bv.w, s3);
    if constexpr (RELU) {
        o0 = fmaxf(o0, 0.f); o1 = fmaxf(o1, 0.f);
        o2 = fmaxf(o2, 0.f); o3 = fmaxf(o3, 0.f);
    }
    bf16x4 ov;
    ov[0] = (__bf16)o0; ov[1] = (__bf16)o1; ov[2] = (__bf16)o2; ov[3] = (__bf16)o3;
    *(bf16x4*)(H + (size_t)r * 256 + lane * 4) = ov;
}

// ---------------- bf16 MFMA GEMM (XCD-swizzled) ----------------
// FLAGS: 1=RELU, 4=bf16 out, 8=transposed out[b][c][i], 16=scores epilogue (implies bf16 out).
// CONCAT: 0 plain; 2 = A row = [A0(256) | wgt-mix of A1/A1+ROWS*512 (512)], K=768.
template<int FLAGS, int CONCAT>
__global__ __launch_bounds__(256) void mfma_gemm(
    const __bf16* __restrict__ A0, const __bf16* __restrict__ A1,
    const __bf16* __restrict__ WT, const float* __restrict__ bias,
    float* __restrict__ Cf, __bf16* __restrict__ Cb, int K, int N,
    const float* __restrict__ aw, float* __restrict__ scp,
    const float* __restrict__ wgt) {
    constexpr int SMEMB = (FLAGS & 8) ? (128 * 129 * 4) : (2 * 128 * 64 * 2);
    __shared__ __attribute__((aligned(16))) char smem[SMEMB];
    __bf16* As = (__bf16*)smem;
    __bf16* Bs = As + 128 * 64;
    int lin = blockIdx.x + 4 * blockIdx.y;
    int nid = xcd_swz(lin, 4 * gridDim.y);
    int bx = nid & 3, by = nid >> 2;
    int t = threadIdx.x, w = t >> 6, l = t & 63;
    int r0 = by * 128, c0 = bx * 128;
    int lr = l & 15, lg = l >> 4;
    int wr = (w >> 1) * 64, wc = (w & 1) * 64;
    f32x4 acc[4][4] = {};
    for (int k0 = 0; k0 < K; k0 += 64) {
        #pragma unroll
        for (int i = 0; i < 4; ++i) {
            int row = (w * 4 + i) * 8 + (l >> 3);
            int c8 = l & 7;
            if constexpr (CONCAT == 2) {
                if (k0 < 256) {
                    gload_lds16(A0 + (size_t)(r0 + row) * 256 + k0 + c8 * 8,
                                As + (w * 4 + i) * 512);
                } else {
                    int kk2 = k0 - 256 + c8 * 8;
                    size_t gr = (size_t)(r0 + row);
                    bf16x8 xa = *(const bf16x8*)(A1 + gr * 512 + kk2);
                    bf16x8 ya = *(const bf16x8*)(A1 + ((size_t)ROWS + gr) * 512 + kk2);
                    float wv = wgt[gr];
                    bf16x8 mx;
                    #pragma unroll
                    for (int j = 0; j < 8; ++j)
                        mx[j] = (__bf16)(wv * (float)xa[j] + (1.f - wv) * (float)ya[j]);
                    *(bf16x8*)(As + (w * 4 + i) * 512 + l * 8) = mx;
                }
            } else {
                gload_lds16(A0 + (size_t)(r0 + row) * K + k0 + c8 * 8,
                            As + (w * 4 + i) * 512);
            }
            gload_lds16(WT + (size_t)(c0 + row) * K + k0 + c8 * 8,
                        Bs + (w * 4 + i) * 512);
        }
        asm volatile("s_waitcnt vmcnt(0)" ::: "memory");
        __syncthreads();
        #pragma unroll
        for (int ks = 0; ks < 2; ++ks) {
            bf16x8 af[4], bfr[4];
            #pragma unroll
            for (int mi = 0; mi < 4; ++mi)
                af[mi] = *(const bf16x8*)(As + (wr + mi * 16 + lr) * 64 + ks * 32 + lg * 8);
            #pragma unroll
            for (int ni = 0; ni < 4; ++ni)
                bfr[ni] = *(const bf16x8*)(Bs + (wc + ni * 16 + lr) * 64 + ks * 32 + lg * 8);
            #pragma unroll
            for (int mi = 0; mi < 4; ++mi)
                #pragma unroll
                for (int ni = 0; ni < 4; ++ni)
                    acc[mi][ni] = __builtin_amdgcn_mfma_f32_16x16x32_bf16(
                        af[mi], bfr[ni], acc[mi][ni], 0, 0, 0);
        }
        __syncthreads();
    }
    if constexpr ((FLAGS & 8) != 0) {
        float* tile = (float*)smem;
        #pragma unroll
        for (int mi = 0; mi < 4; ++mi)
            #pragma unroll
            for (int r = 0; r < 4; ++r) {
                int rrow = wr + mi * 16 + lg * 4 + r;
                #pragma unroll
                for (int ni = 0; ni < 4; ++ni) {
                    int ccol = wc + ni * 16 + lr;
                    float v = acc[mi][ni][r];
                    if (bias) v += bias[c0 + ccol];
                    if constexpr ((FLAGS & 1) != 0) v = fmaxf(v, 0.f);
                    tile[rrow * 129 + ccol] = v;
                }
            }
        __syncthreads();
        int cc = t >> 6, rr2 = t & 63;
        #pragma unroll
        for (int cs = 0; cs < 128; cs += 4) {
            #pragma unroll
            for (int h = 0; h < 2; ++h) {
                int row = r0 + rr2 + h * 64;
                int bb = row / NPT, ii = row - bb * NPT;
                Cf[((size_t)bb * 512 + (c0 + cc + cs)) * NPT + ii] =
                    tile[(rr2 + h * 64) * 129 + cc + cs];
            }
        }
    } else if constexpr ((FLAGS & 16) != 0) {
        int half = (r0 >= ROWS) ? 1 : 0;
        float ps[4][4] = {};
        #pragma unroll
        for (int mi = 0; mi < 4; ++mi)
            #pragma unroll
            for (int r = 0; r < 4; ++r) {
                int row = r0 + wr + mi * 16 + lg * 4 + r;
                #pragma unroll
                for (int ni = 0; ni < 4; ++ni) {
                    int col = c0 + wc + ni * 16 + lr;
                    float v = acc[mi][ni][r] + bias[col];
                    Cb[(size_t)row * N + col] = (__bf16)v;
                    ps[mi][r] = fmaf(v, aw[half * 512 + col], ps[mi][r]);
                }
            }
        #pragma unroll
        for (int m = 1; m <= 8; m <<= 1)
            #pragma unroll
            for (int mi = 0; mi < 4; ++mi)
                #pragma unroll
                for (int r = 0; r < 4; ++r)
                    ps[mi][r] += __shfl_xor(ps[mi][r], m, 64);
        if (lr == 0) {
            int slot = half * 8 + bx * 2 + (w & 1);
            #pragma unroll
            for (int mi = 0; mi < 4; ++mi)
                #pragma unroll
                for (int r = 0; r < 4; ++r) {
                    int sr = r0 - half * ROWS + wr + mi * 16 + lg * 4 + r;
                    scp[(size_t)slot * ROWS + sr] = ps[mi][r];
                }
        }
    } else {
        #pragma unroll
        for (int mi = 0; mi < 4; ++mi) {
            #pragma unroll
            for (int r = 0; r < 4; ++r) {
                int row = r0 + wr + mi * 16 + lg * 4 + r;
                #pragma unroll
                for (int ni = 0; ni < 4; ++ni) {
                    int col = c0 + wc + ni * 16 + lr;
                    float v = acc[mi][ni][r];
                    if (bias) v += bias[col];
                    if constexpr ((FLAGS & 1) != 0) v = fmaxf(v, 0.f);
                    if constexpr ((FLAGS & 4) != 0)
                        Cb[(size_t)row * N + col] = (__bf16)v;
                    else
                        Cf[(size_t)row * N + col] = v;
                }
            }
        }
    }
}

// ------- single-dispatch softmax: per-block partials + fence/atomic last-block combine -------
__global__ __launch_bounds__(256) void softmax_all(const float* __restrict__ scp,
        const float* __restrict__ ab, float* __restrict__ scores,
        float* __restrict__ mpart, float* __restrict__ spart,
        int* __restrict__ cnt, float* __restrict__ wgt) {
    __shared__ float red[256];
    __shared__ float MS[2];
    __shared__ bool islast;
    int t = threadIdx.x;
    int sr = blockIdx.x * 256 + t;              // 49*256 = ROWS exactly
    float s = ab[0];
    #pragma unroll
    for (int i = 0; i < 16; ++i) s += scp[(size_t)i * ROWS + sr];
    scores[sr] = s;
    red[t] = s; __syncthreads();
    for (int off = 128; off; off >>= 1) {
        if (t < off) red[t] = fmaxf(red[t], red[t + off]);
        __syncthreads();
    }
    float mb = red[0]; __syncthreads();
    red[t] = expf(s - mb); __syncthreads();
    for (int off = 128; off; off >>= 1) {
        if (t < off) red[t] += red[t + off];
        __syncthreads();
    }
    if (t == 0) {
        mpart[blockIdx.x] = mb;
        spart[blockIdx.x] = red[0];
        __threadfence();
        int old = atomicAdd(cnt, 1);
        islast = (old == 48);
    }
    __syncthreads();
    if (!islast) return;
    __threadfence();
    if (t == 0) {
        float M = mpart[0];
        for (int i = 1; i < 49; ++i) M = fmaxf(M, mpart[i]);
        float S = 0.f;
        for (int i = 0; i < 49; ++i) S += spart[i] * expf(mpart[i] - M);
        MS[0] = M; MS[1] = S;
        cnt[0] = 0;
    }
    __syncthreads();
    float M = MS[0], denom = MS[1];
    for (int i = t; i < ROWS; i += 256)
        wgt[i] = expf(scores[i] - M) / denom;
}

extern "C" void kernel_launch(void* const* d_in, const int* in_sizes, int n_in,
                              void* d_out, int out_size, void* d_ws, size_t ws_size,
                              hipStream_t stream) {
    (void)in_sizes; (void)n_in; (void)out_size; (void)ws_size;
    const float* x       = (const float*)d_in[0];
    const float* fc1_w   = (const float*)d_in[1];
    const float* fc1_b   = (const float*)d_in[2];
    const float* fc2_w   = (const float*)d_in[3];
    const float* fc2_b   = (const float*)d_in[4];
    const float* fce_w   = (const float*)d_in[5];
    const float* fce_b   = (const float*)d_in[6];
    const float* inout_w = (const float*)d_in[7];
    const float* inout_b = (const float*)d_in[8];
    const float* attn_w  = (const float*)d_in[9];
    const float* attn_b  = (const float*)d_in[10];
    const float* upd_w   = (const float*)d_in[11];
    const float* upd_b   = (const float*)d_in[12];
    const float* kp_w    = (const float*)d_in[13];
    const float* kp_b    = (const float*)d_in[14];
    const float* enc_w   = (const float*)d_in[15];
    const float* enc_b   = (const float*)d_in[16];
    const float* mu_w    = (const float*)d_in[17];
    const float* mu_b    = (const float*)d_in[18];
    const float* dec_w   = (const float*)d_in[19];
    const float* dec_b   = (const float*)d_in[20];
    float* out = (float*)d_out;

    char* base = (char*)d_ws;
    size_t o = 0;
    auto alloc = [&](size_t bytes) -> void* {
        void* p = base + o;
        o += (bytes + 255) & ~(size_t)255;
        return p;
    };
    float* qsp    = (float*)alloc((size_t)4 * 64 * 256 * 4);        //  0.26 MB
    float* degf   = (float*)alloc(ROWS * 4);
    float* scores = (float*)alloc(ROWS * 4);
    float* wgt    = (float*)alloc(ROWS * 4);
    int*   kint   = (int*)  alloc(ROWS * 4);
    float* KW1    = (float*)alloc(256 * 64 * 4);
    float* kb1    = (float*)alloc(64 * 4);
    float* KW2    = (float*)alloc(64 * 9 * 4);
    float* kb2    = (float*)alloc(9 * 4);
    float* bcomp  = (float*)alloc(512 * 4);
    float* scp    = (float*)alloc((size_t)16 * ROWS * 4);           //  0.80 MB
    float* mpart  = (float*)alloc(64 * 4);
    float* spart  = (float*)alloc(64 * 4);
    int*   smcnt  = (int*)  alloc(256);
    int*   nbr    = (int*)  alloc((size_t)128 * NPT * KNB * 4);     //  0.80 MB
    char*  regD   = (char*) alloc((size_t)ROWS * 512 * 2);          // 12.85 MB
    __bf16* XB    = (__bf16*)alloc((size_t)ROWS * 256 * 2);         //  6.42 MB
    __bf16* H1    = (__bf16*)alloc((size_t)2 * ROWS * 256 * 2);     // 12.85 MB
    __bf16* H2    = (__bf16*)alloc((size_t)2 * ROWS * 256 * 2);     // 12.85 MB
    char*  regAGG = (char*) alloc((size_t)2 * ROWS * 512 * 4);      // 51.38 MB
    __bf16* W1catT= (__bf16*)alloc((size_t)512 * 256 * 2);
    __bf16* W2catT= (__bf16*)alloc((size_t)512 * 256 * 2);
    __bf16* fcet  = (__bf16*)alloc((size_t)512 * 256 * 2);
    __bf16* updC  = (__bf16*)alloc((size_t)512 * 768 * 2);
    // --- aliases (stream-order safe) ---
    __bf16* P1buf = (__bf16*)regD;                 // stage-1 P, dead after combine1
    _Float16* XSPH = (_Float16*)regAGG;            // [0, 8.39MB), dead after gram
    _Float16* XSPL = XSPH + (size_t)64 * 256 * 256;// [8.39, 16.78MB)
    float* Dw     = (float*)(regAGG + (size_t)17 * 1024 * 1024);  // 21.2MB, dead after topk
    __bf16* P2buf = (__bf16*)regAGG;               // stage-2 P (25.7MB), after topk
    __bf16* AGGb  = (__bf16*)regAGG;               // fce output (bf16), 25.7 MB
    __bf16* XAGGb = AGGb;

    // ---- K1: trans_split+qs + full prep (f32 ILP compose for updC/bcomp) ----
    front_kernel<<<1766, 256, 0, stream>>>(x, XSPH, XSPL, XB, qsp,
                                           fc1_w, fc2_w, fce_w, upd_w,
                                           kp_w, kp_b, enc_w, enc_b,
                                           mu_w, mu_b, dec_w, dec_b,
                                           inout_w, inout_b, upd_b,
                                           W1catT, W2catT, fcet, updC,
                                           KW1, kb1, KW2, kb2, bcomp, smcnt);

    // ---- K2: gram 64x64 double-buffered (dist -> HBM) + collapsed k-predictor ----
    gram_kint<<<2832, 256, 0, stream>>>(XSPH, XSPL, qsp, Dw, x,
                                        KW1, kb1, KW2, kb2, kint, degf);

    // ---- K3: topk + P1 projection GEMM ----
    topk_p1<<<784, 256, 0, stream>>>(Dw, nbr, XB, W1catT, P1buf);

    // ---- EdgeConv combine 1 ----
    combine_kernel<1, 1><<<2 * ROWS / 4, 256, 0, stream>>>(
        P1buf, nbr, kint, degf, fc1_b, H1);

    // ---- EdgeConv stage 2 ----
    mfma_gemm<4, 0><<<dim3(4, 196), 256, 0, stream>>>(
        H1, nullptr, W2catT, nullptr, nullptr, P2buf, 256, 512,
        nullptr, nullptr, nullptr);
    combine_kernel<2, 0><<<2 * ROWS / 4, 256, 0, stream>>>(
        P2buf, nbr, kint, degf, fc2_b, H2);

    // ---- fce (bf16 out + fused attention-score partials) ----
    mfma_gemm<20, 0><<<dim3(4, 196), 256, 0, stream>>>(
        H2, nullptr, fcet, fce_b, nullptr, AGGb, 256, 512,
        attn_w, scp, nullptr);

    // ---- softmax (single dispatch, deterministic last-block combine) ----
    softmax_all<<<49, 256, 0, stream>>>(scp, attn_b, scores, mpart, spart,
                                        smcnt, wgt);

    // ---- final upd GEMM: inline wgt-mix A-staging, composed inout, transposed out ----
    mfma_gemm<9, 2><<<dim3(4, 98), 256, 0, stream>>>(
        XB, XAGGb, updC, bcomp, out, nullptr, 768, 512,
        nullptr, nullptr, wgt);
}

// Round 18
// 210.418 us; speedup vs baseline: 1.0648x; 1.0037x over previous
//
#include <hip/hip_runtime.h>
#include <cstddef>
#include <cstdint>

constexpr int BATCH = 64;
constexpr int CH    = 256;
constexpr int NPT   = 196;
constexpr int ROWS  = BATCH * NPT;   // 12544
constexpr int BSTRIDE = CH * NPT;    // 50176
constexpr int KNB   = 8;             // position 8 (9th) is never valid: k_int <= 8
constexpr int DSTR  = 208;           // D row stride (floats), 4 aligned 52-col quarters

typedef __bf16 bf16x8 __attribute__((ext_vector_type(8)));
typedef __bf16 bf16x4 __attribute__((ext_vector_type(4)));
typedef _Float16 f16x8 __attribute__((ext_vector_type(8)));
typedef float  f32x4  __attribute__((ext_vector_type(4)));
typedef unsigned long long u64;

__device__ __forceinline__ int src_batch(int b) {
    return (b & ~15) | ((b + 1) & 15);
}

__device__ __forceinline__ void gload_lds16(const void* g, void* l) {
    __builtin_amdgcn_global_load_lds(
        (const __attribute__((address_space(1))) void*)g,
        (__attribute__((address_space(3))) void*)l, 16, 0, 0);
}

// bijective XCD swizzle (m204): nwg must be %8==0
__device__ __forceinline__ int xcd_swz(int lin, int nwg) {
    int q = nwg >> 3;
    return (lin & 7) * q + (lin >> 3);
}

// ------- K1: trans_split+qs (0..1023) | prep (1024..1765) -------
__global__ __launch_bounds__(256) void front_kernel(const float* __restrict__ x,
        _Float16* __restrict__ XH, _Float16* __restrict__ XL,
        __bf16* __restrict__ XB, float* __restrict__ qsp,
        const float* __restrict__ fc1_w, const float* __restrict__ fc2_w,
        const float* __restrict__ fce_w, const float* __restrict__ upd_w,
        const float* __restrict__ kp_w, const float* __restrict__ kp_b,
        const float* __restrict__ enc_w, const float* __restrict__ enc_b,
        const float* __restrict__ mu_w, const float* __restrict__ mu_b,
        const float* __restrict__ dec_w, const float* __restrict__ dec_b,
        const float* __restrict__ inout_w, const float* __restrict__ inout_b,
        const float* __restrict__ upd_b,
        __bf16* __restrict__ W1catT, __bf16* __restrict__ W2catT,
        __bf16* __restrict__ fcet, __bf16* __restrict__ updC,
        float* __restrict__ KW1, float* __restrict__ kb1,
        float* __restrict__ KW2, float* __restrict__ kb2,
        float* __restrict__ bcomp, int* __restrict__ smcnt) {
    __shared__ __attribute__((aligned(16))) char smem[16896];
    float (*tile)[65] = (float(*)[65])smem;
    int bid = blockIdx.x;
    int t = threadIdx.x;
    if (bid < 1024) {
        // ---- trans_split + qs quadrant partial ----
        int m0 = (bid & 3) * 64, c0 = ((bid >> 2) & 3) * 64, b = bid >> 4;
        const float* xb = x + (size_t)b * BSTRIDE;
        #pragma unroll
        for (int s = 0; s < 16; ++s) {
            int idx = s * 256 + t;
            int cc = idx >> 6, mm = idx & 63;
            int m = m0 + mm;
            float v = (m < NPT) ? xb[(size_t)(c0 + cc) * NPT + m] : 0.f;
            tile[cc][mm] = v;
            if (m < NPT)
                XB[(size_t)b * BSTRIDE + (size_t)(c0 + cc) * NPT + m] = (__bf16)v;
        }
        __syncthreads();
        #pragma unroll
        for (int s = 0; s < 16; ++s) {
            int idx = s * 256 + t;
            int mm = idx >> 6, cc = idx & 63;
            float v = tile[cc][mm];
            _Float16 h = (_Float16)v;
            size_t off = ((size_t)b * 256 + (m0 + mm)) * 256 + c0 + cc;
            XH[off] = h;
            XL[off] = (_Float16)(v - (float)h);
        }
        if (t < 64) {
            float acc = 0.f;
            #pragma unroll
            for (int cc = 0; cc < 64; ++cc) {
                float v = tile[cc][t];
                acc = fmaf(v, v, acc);
            }
            qsp[(size_t)(c0 >> 6) * 16384 + b * 256 + m0 + t] = acc;
        }
    } else {
        // ---- prep (weight transposes + compositions) ----
        int pbid = bid - 1024;
        if (pbid == 0 && t == 0) smcnt[0] = 0;   // reset softmax counter each call
        if (pbid < 64) {
            const float* W = (pbid < 32) ? fc1_w : fc2_w;
            __bf16* WT = (pbid < 32) ? W1catT : W2catT;
            int local = pbid & 31;
            int n0 = (local >> 2) * 64, k0 = (local & 3) * 64;
            #pragma unroll
            for (int s = 0; s < 16; ++s) {
                int idx = s * 256 + t;
                int kk = idx >> 6, nn = idx & 63;
                float v;
                if (n0 < 256)
                    v = W[(size_t)(k0 + kk) * 256 + n0 + nn] -
                        W[(size_t)(k0 + kk + 256) * 256 + n0 + nn];
                else
                    v = W[(size_t)(k0 + kk + 256) * 256 + (n0 - 256) + nn];
                tile[kk][nn] = v;
            }
            __syncthreads();
            #pragma unroll
            for (int s = 0; s < 16; ++s) {
                int idx = s * 256 + t;
                int nn = idx >> 6, kk = idx & 63;
                WT[(size_t)(n0 + nn) * 256 + k0 + kk] = (__bf16)tile[kk][nn];
            }
        } else if (pbid < 96) {
            int local = pbid - 64;
            int n0 = (local >> 2) * 64, k0 = (local & 3) * 64;
            #pragma unroll
            for (int s = 0; s < 16; ++s) {
                int idx = s * 256 + t;
                int kk = idx >> 6, nn = idx & 63;
                tile[kk][nn] = fce_w[(size_t)(k0 + kk) * 512 + n0 + nn];
            }
            __syncthreads();
            #pragma unroll
            for (int s = 0; s < 16; ++s) {
                int idx = s * 256 + t;
                int nn = idx >> 6, kk = idx & 63;
                fcet[(size_t)(n0 + nn) * 256 + k0 + kk] = (__bf16)tile[kk][nn];
            }
        } else if (pbid < 160) {
            int local = pbid - 96;                       // 0..63
            int k0 = (local >> 3) * 64, n0 = (local & 7) * 64;
            #pragma unroll
            for (int s = 0; s < 16; ++s) {
                int idx = s * 256 + t;
                int kk = idx >> 6, nn = idx & 63;
                tile[kk][nn] = upd_w[(size_t)(512 + k0 + kk) * 512 + n0 + nn];
            }
            __syncthreads();
            #pragma unroll
            for (int s = 0; s < 16; ++s) {
                int idx = s * 256 + t;
                int nn = idx >> 6, kk = idx & 63;
                updC[(size_t)(n0 + nn) * 768 + 256 + k0 + kk] = (__bf16)tile[kk][nn];
            }
        } else if (pbid < 224) {
            // KW1 compose stays f64 (argmax-sensitive)
            int i = (pbid - 160) * 4 + (t >> 6);
            int j = t & 63;
            double acc = 0.0;
            for (int k = 0; k < 500; ++k)
                acc += (double)kp_w[(size_t)i * 500 + k] * (double)enc_w[(size_t)k * 64 + j];
            KW1[i * 64 + j] = (float)acc;
        } else if (pbid == 224) {
            int j = t;
            if (j < 64) {
                double acc = (double)enc_b[j];
                for (int k = 0; k < 500; ++k)
                    acc += (double)kp_b[k] * (double)enc_w[(size_t)k * 64 + j];
                kb1[j] = (float)acc;
            }
        } else if (pbid < 228) {
            int e = (pbid - 225) * 256 + t;
            if (e < 576) {
                int i = e / 9, j = e - (e / 9) * 9;
                double acc = 0.0;
                for (int k = 0; k < 32; ++k)
                    acc += (double)mu_w[(size_t)i * 32 + k] * (double)dec_w[(size_t)k * 9 + j];
                KW2[e] = (float)acc;
            } else if (e < 585) {
                int j = e - 576;
                double acc = (double)dec_b[j];
                for (int k = 0; k < 32; ++k)
                    acc += (double)mu_b[k] * (double)dec_w[(size_t)k * 9 + j];
                kb2[j] = (float)acc;
            }
        } else if (pbid < 740) {
            // updC compose: f32, 4 split accumulators
            int e = (pbid - 228) * 256 + t;              // 0..131071
            int k = e >> 9, n = e & 511;
            const float* iw = inout_w + (size_t)k * 512;
            float a0 = 0.f, a1 = 0.f, a2 = 0.f, a3 = 0.f;
            for (int j = 0; j < 512; j += 4) {
                a0 = fmaf(iw[j + 0], upd_w[(size_t)(j + 0) * 512 + n], a0);
                a1 = fmaf(iw[j + 1], upd_w[(size_t)(j + 1) * 512 + n], a1);
                a2 = fmaf(iw[j + 2], upd_w[(size_t)(j + 2) * 512 + n], a2);
                a3 = fmaf(iw[j + 3], upd_w[(size_t)(j + 3) * 512 + n], a3);
            }
            updC[(size_t)n * 768 + k] = (__bf16)((a0 + a1) + (a2 + a3));
        } else {
            // bcomp: f32, 4 split accumulators
            int n = (pbid - 740) * 256 + t;              // 0..511
            float a0 = upd_b[n], a1 = 0.f, a2 = 0.f, a3 = 0.f;
            for (int j = 0; j < 512; j += 4) {
                a0 = fmaf(inout_b[j + 0], upd_w[(size_t)(j + 0) * 512 + n], a0);
                a1 = fmaf(inout_b[j + 1], upd_w[(size_t)(j + 1) * 512 + n], a1);
                a2 = fmaf(inout_b[j + 2], upd_w[(size_t)(j + 2) * 512 + n], a2);
                a3 = fmaf(inout_b[j + 3], upd_w[(size_t)(j + 3) * 512 + n], a3);
            }
            bcomp[n] = (a0 + a1) + (a2 + a3);
        }
    }
}

// ------- K2 mega-kernel: gram 64x64 dbuf BK=32 XOR-swizzled (0..2047) | k-predictor -------
// LDS slot swizzle (T2, rule 21): logical k-slot s of row r stored at physical
// slot s ^ ((r>>1)&3). Dest stays lane-linear; SOURCE is pre-swizzled; reads
// apply the same XOR. Whole 16B slots permute -> MFMA operands bit-identical.
__global__ __launch_bounds__(256) void gram_kint(const _Float16* __restrict__ XH,
        const _Float16* __restrict__ XL, const float* __restrict__ qsp,
        float* __restrict__ Dw, const float* __restrict__ x,
        const float* __restrict__ W1, const float* __restrict__ b1,
        const float* __restrict__ W2, const float* __restrict__ b2,
        int* __restrict__ kint, float* __restrict__ degf) {
    __shared__ __attribute__((aligned(16))) char smem[32768];
    int bid = blockIdx.x;
    int t = threadIdx.x;
    if (bid < 2048) {
        int nid = xcd_swz(bid, 2048);
        int job = nid >> 4;
        int tile = nid & 15;
        int by = tile >> 2, bx = tile & 3;
        int r0 = by * 64, c0 = bx * 64;
        int qb = (job < 64) ? job : job - 64;
        int kb = (job < 64) ? qb : src_batch(qb);
        int w = t >> 6, l = t & 63;
        int lr = l & 15, lg = l >> 4;
        int wr = (w >> 1) * 32, wc = (w & 1) * 32;
        const _Float16* qh = XH + (size_t)qb * 65536;
        const _Float16* ql = XL + (size_t)qb * 65536;
        const _Float16* kh = XH + (size_t)kb * 65536;
        const _Float16* kl = XL + (size_t)kb * 65536;
        int srow = w * 16 + (l >> 2);
        // pre-swizzled source k-slot: s = (l&3) ^ ((row>>1)&3) = (l&3) ^ ((l>>3)&3)
        int scb = (((l & 3) ^ ((l >> 3) & 3))) * 8;
        f32x4 acc[2][2] = {};
        auto stage = [&](int k0, int bsel) {
            _Float16* base = (_Float16*)(smem + bsel * 16384);
            size_t goA = (size_t)(r0 + srow) * 256 + k0 + scb;
            size_t goB = (size_t)(c0 + srow) * 256 + k0 + scb;
            gload_lds16(qh + goA, base + w * 512);
            gload_lds16(ql + goA, base + 2048 + w * 512);
            gload_lds16(kh + goB, base + 4096 + w * 512);
            gload_lds16(kl + goB, base + 6144 + w * 512);
        };
        stage(0, 0);
        #pragma unroll
        for (int ks8 = 0; ks8 < 8; ++ks8) {
            if (ks8 < 7) {
                stage((ks8 + 1) * 32, (ks8 + 1) & 1);
                asm volatile("s_waitcnt vmcnt(4)" ::: "memory");
            } else {
                asm volatile("s_waitcnt vmcnt(0)" ::: "memory");
            }
            __syncthreads();
            _Float16* base = (_Float16*)(smem + (ks8 & 1) * 16384);
            _Float16* Ah = base;
            _Float16* Al = base + 2048;
            _Float16* Bh = base + 4096;
            _Float16* Bl = base + 6144;
            f16x8 ah[2], alv[2], bh[2], blv[2];
            #pragma unroll
            for (int mi = 0; mi < 2; ++mi) {
                int rowA = wr + mi * 16 + lr;
                int pA = (lg ^ ((rowA >> 1) & 3)) * 8;
                ah[mi]  = *(const f16x8*)(Ah + rowA * 32 + pA);
                alv[mi] = *(const f16x8*)(Al + rowA * 32 + pA);
            }
            #pragma unroll
            for (int ni = 0; ni < 2; ++ni) {
                int rowB = wc + ni * 16 + lr;
                int pB = (lg ^ ((rowB >> 1) & 3)) * 8;
                bh[ni]  = *(const f16x8*)(Bh + rowB * 32 + pB);
                blv[ni] = *(const f16x8*)(Bl + rowB * 32 + pB);
            }
            #pragma unroll
            for (int mi = 0; mi < 2; ++mi)
                #pragma unroll
                for (int ni = 0; ni < 2; ++ni) {
                    acc[mi][ni] = __builtin_amdgcn_mfma_f32_16x16x32_f16(
                        ah[mi], bh[ni], acc[mi][ni], 0, 0, 0);
                    acc[mi][ni] = __builtin_amdgcn_mfma_f32_16x16x32_f16(
                        ah[mi], blv[ni], acc[mi][ni], 0, 0, 0);
                    acc[mi][ni] = __builtin_amdgcn_mfma_f32_16x16x32_f16(
                        alv[mi], bh[ni], acc[mi][ni], 0, 0, 0);
                }
            __syncthreads();
        }
        float ksv[2];
        #pragma unroll
        for (int ni = 0; ni < 2; ++ni) {
            int col = c0 + wc + ni * 16 + lr;
            if (col < NPT) {
                size_t o0 = (size_t)kb * 256 + col;
                ksv[ni] = ((qsp[o0] + qsp[16384 + o0]) + qsp[32768 + o0]) +
                          qsp[49152 + o0];
            } else ksv[ni] = 0.f;
        }
        #pragma unroll
        for (int mi = 0; mi < 2; ++mi) {
            #pragma unroll
            for (int r = 0; r < 4; ++r) {
                if (r0 + wr + mi * 16 + r >= NPT) continue;  // wave-uniform skip
                int grow = r0 + wr + mi * 16 + lg * 4 + r;
                if (grow >= NPT) continue;
                size_t o0 = (size_t)qb * 256 + grow;
                float qq = ((qsp[o0] + qsp[16384 + o0]) + qsp[32768 + o0]) +
                           qsp[49152 + o0];
                size_t rbase = ((size_t)job * NPT + grow) * DSTR;
                #pragma unroll
                for (int ni = 0; ni < 2; ++ni) {
                    int col = c0 + wc + ni * 16 + lr;
                    if (col < NPT)
                        Dw[rbase + col] = qq - 2.f * acc[mi][ni][r] + ksv[ni];
                }
            }
        }
    } else {
        // ---- collapsed k-predictor ----
        float (*xr)[256] = (float(*)[256])smem;                  // 16384 B
        float (*ebuf)[64] = (float(*)[64])(smem + 16384);        //  4096 B
        float (*lg2)[9]  = (float(*)[9])(smem + 20480);          //   576 B
        int r0 = (bid - 2048) * 16;
        const float4* xg = (const float4*)(x + (size_t)r0 * 256);
        float4* xs = (float4*)&xr[0][0];
        #pragma unroll
        for (int s = 0; s < 4; ++s) xs[s * 256 + t] = xg[s * 256 + t];
        __syncthreads();
        int w = t >> 6, l = t & 63;
        {
            float bb = b1[l];
            float a0 = bb, a1 = bb, a2 = bb, a3 = bb;
            const float* x0 = xr[w * 4 + 0];
            const float* x1 = xr[w * 4 + 1];
            const float* x2 = xr[w * 4 + 2];
            const float* x3 = xr[w * 4 + 3];
            for (int c = 0; c < 256; ++c) {
                float wv = W1[c * 64 + l];
                a0 = fmaf(x0[c], wv, a0);
                a1 = fmaf(x1[c], wv, a1);
                a2 = fmaf(x2[c], wv, a2);
                a3 = fmaf(x3[c], wv, a3);
            }
            ebuf[w * 4 + 0][l] = fmaxf(a0, 0.f);
            ebuf[w * 4 + 1][l] = fmaxf(a1, 0.f);
            ebuf[w * 4 + 2][l] = fmaxf(a2, 0.f);
            ebuf[w * 4 + 3][l] = fmaxf(a3, 0.f);
        }
        __syncthreads();
        int rr = t >> 4, cc = t & 15;
        if (cc < 9) {
            float acc = b2[cc];
            for (int j = 0; j < 64; ++j)
                acc = fmaf(ebuf[rr][j], W2[j * 9 + cc], acc);
            lg2[rr][cc] = acc;
        }
        __syncthreads();
        if (cc == 0) {
            float best = lg2[rr][0];
            int bi = 0;
            #pragma unroll
            for (int j = 1; j < 9; ++j)
                if (lg2[rr][j] > best) { best = lg2[rr][j]; bi = j; }
            kint[r0 + rr] = bi;
            degf[r0 + rr] = (float)bi;
        }
    }
}

// ------- K3: topk (0..391) | P1 projection GEMM (392..783) -------
__global__ __launch_bounds__(256) void topk_p1(const float* __restrict__ Dw,
        int* __restrict__ nbr, const __bf16* __restrict__ XB,
        const __bf16* __restrict__ W1catT, __bf16* __restrict__ P1) {
    __shared__ __attribute__((aligned(16))) char smem[32768];
    int bid = blockIdx.x;
    int t = threadIdx.x;
    if (bid < 392) {
        // ---- top-8: thread per (row, 52-col quarter) + in-block 4-way merge ----
        u64 (*lists)[4][8] = (u64(*)[4][8])smem;
        int lrow = t >> 2, q = t & 3;
        int rowid = bid * 64 + lrow;              // 392*64 = 25088 exactly
        const float* rp = Dw + (size_t)rowid * DSTR + q * 52;
        u64 kreg[8];
        #pragma unroll
        for (int p = 0; p < 8; ++p) kreg[p] = ~0ull;
        for (int s4 = 0; s4 < 13; ++s4) {
            f32x4 dv = *(const f32x4*)(rp + s4 * 4);
            #pragma unroll
            for (int e = 0; e < 4; ++e) {
                int col = q * 52 + s4 * 4 + e;
                unsigned u = __float_as_uint(dv[e]);
                u = (u & 0x80000000u) ? ~u : (u | 0x80000000u);
                u64 key = (col < NPT) ? (((u64)u << 32) | (unsigned)col) : ~0ull;
                if (key < kreg[7]) {
                    #pragma unroll
                    for (int p = 0; p < 8; ++p) {
                        u64 mn = (key < kreg[p]) ? key : kreg[p];
                        u64 mx = (key < kreg[p]) ? kreg[p] : key;
                        kreg[p] = mn; key = mx;
                    }
                }
            }
        }
        #pragma unroll
        for (int p = 0; p < 8; ++p) lists[lrow][q][p] = kreg[p];
        __syncthreads();
        if (q == 0) {
            const u64* c = &lists[lrow][0][0];
            int p0 = 0, p1 = 0, p2 = 0, p3 = 0;
            #pragma unroll
            for (int it = 0; it < 8; ++it) {
                u64 v0 = c[p0], v1 = c[8 + p1], v2 = c[16 + p2], v3 = c[24 + p3];
                u64 best = v0; int bj = 0;
                if (v1 < best) { best = v1; bj = 1; }
                if (v2 < best) { best = v2; bj = 2; }
                if (v3 < best) { best = v3; bj = 3; }
                if (bj == 0) p0 = (p0 < 7) ? p0 + 1 : 7;
                else if (bj == 1) p1 = (p1 < 7) ? p1 + 1 : 7;
                else if (bj == 2) p2 = (p2 < 7) ? p2 + 1 : 7;
                else p3 = (p3 < 7) ? p3 + 1 : 7;
                nbr[(size_t)rowid * KNB + it] = (int)(best & 0xffffffffu);
            }
        }
    } else {
        // ---- P1 projection: P1 = bf16(XB @ W1catT) ----
        __bf16* As = (__bf16*)smem;
        __bf16* Bs = As + 128 * 64;
        int lin = bid - 392;
        int nid = xcd_swz(lin, 392);
        int bx = nid & 3, by = nid >> 2;
        int w = t >> 6, l = t & 63;
        int r0 = by * 128, c0 = bx * 128;
        int lr = l & 15, lg = l >> 4;
        int wr = (w >> 1) * 64, wc = (w & 1) * 64;
        constexpr int K = 256, N = 512;
        f32x4 acc[4][4] = {};
        for (int k0 = 0; k0 < K; k0 += 64) {
            #pragma unroll
            for (int i = 0; i < 4; ++i) {
                int row = (w * 4 + i) * 8 + (l >> 3);
                int c8 = l & 7;
                gload_lds16(XB + (size_t)(r0 + row) * K + k0 + c8 * 8,
                            As + (w * 4 + i) * 512);
                gload_lds16(W1catT + (size_t)(c0 + row) * K + k0 + c8 * 8,
                            Bs + (w * 4 + i) * 512);
            }
            asm volatile("s_waitcnt vmcnt(0)" ::: "memory");
            __syncthreads();
            #pragma unroll
            for (int ks = 0; ks < 2; ++ks) {
                bf16x8 af[4], bfr[4];
                #pragma unroll
                for (int mi = 0; mi < 4; ++mi)
                    af[mi] = *(const bf16x8*)(As + (wr + mi * 16 + lr) * 64 + ks * 32 + lg * 8);
                #pragma unroll
                for (int ni = 0; ni < 4; ++ni)
                    bfr[ni] = *(const bf16x8*)(Bs + (wc + ni * 16 + lr) * 64 + ks * 32 + lg * 8);
                #pragma unroll
                for (int mi = 0; mi < 4; ++mi)
                    #pragma unroll
                    for (int ni = 0; ni < 4; ++ni)
                        acc[mi][ni] = __builtin_amdgcn_mfma_f32_16x16x32_bf16(
                            af[mi], bfr[ni], acc[mi][ni], 0, 0, 0);
            }
            __syncthreads();
        }
        #pragma unroll
        for (int mi = 0; mi < 4; ++mi) {
            #pragma unroll
            for (int r = 0; r < 4; ++r) {
                int row = r0 + wr + mi * 16 + lg * 4 + r;
                #pragma unroll
                for (int ni = 0; ni < 4; ++ni) {
                    int col = c0 + wc + ni * 16 + lr;
                    P1[(size_t)row * N + col] = (__bf16)acc[mi][ni][r];
                }
            }
        }
    }
}

// ------- combine: H[r] = (relu?)( deg*(Pa[self]+bias) + sum_nbr Pb ), XCD-swizzled -------
template<int STAGE, int RELU>
__global__ __launch_bounds__(256) void combine_kernel(const __bf16* __restrict__ P,
        const int* __restrict__ nbr, const int* __restrict__ kint_,
        const float* __restrict__ degf, const float* __restrict__ bias,
        __bf16* __restrict__ H) {
    int g = threadIdx.x >> 6, lane = threadIdx.x & 63;
    int nid = xcd_swz(blockIdx.x, 2 * ROWS / 4);
    int r = nid * 4 + g;                        // 0..2*ROWS
    int branch = (r >= ROWS);
    int rr = r - branch * ROWS;
    int b = rr / NPT, i = rr - b * NPT;
    size_t srow, mbase;
    if constexpr (STAGE == 1) {
        int fb = branch ? src_batch(b) : b;
        srow = (size_t)fb * NPT + i;
        mbase = (size_t)fb * NPT;
    } else {
        srow = (size_t)r;
        mbase = (size_t)branch * ROWS + (size_t)b * NPT;
    }
    const int* nb = nbr + (size_t)branch * ((size_t)ROWS * KNB) + (size_t)rr * KNB;
    bf16x4 sv = *(const bf16x4*)(P + srow * 512 + lane * 4);
    float4 bv = *(const float4*)(bias + lane * 4);
    float s0 = 0.f, s1 = 0.f, s2 = 0.f, s3 = 0.f;
    int kk = kint_[rr];
    for (int tt = 0; tt < kk; ++tt) {
        int m = nb[tt];
        bf16x4 v = *(const bf16x4*)(P + (mbase + m) * 512 + 256 + lane * 4);
        s0 += (float)v[0]; s1 += (float)v[1]; s2 += (float)v[2]; s3 += (float)v[3];
    }
    float dg = degf[rr];
    float o0 = fmaf(dg, (float)sv[0] + bv.x, s0);
    float o1 = fmaf(dg, (float)sv[1] + bv.y, s1);
    float o2 = fmaf(dg, (float)sv[2] + bv.z, s2);
    float o3 = fmaf(dg, (float)sv[3] + bv.w, s3);
    if constexpr (RELU) {
        o0 = fmaxf(o0, 0.f); o1 = fmaxf(o1, 0.f);
        o2 = fmaxf(o2, 0.f); o3 = fmaxf(o3, 0.f);
    }
    bf16x4 ov;
    ov[0] = (__bf16)o0; ov[1] = (__bf16)o1; ov[2] = (__bf16)o2; ov[3] = (__bf16)o3;
    *(bf16x4*)(H + (size_t)r * 256 + lane * 4) = ov;
}

// ---------------- bf16 MFMA GEMM (XCD-swizzled) ----------------
// FLAGS: 1=RELU, 4=bf16 out, 8=transposed out[b][c][i], 16=scores epilogue (implies bf16 out).
// CONCAT: 0 plain; 2 = A row = [A0(256) | wgt-mix of A1/A1+ROWS*512 (512)], K=768.
template<int FLAGS, int CONCAT>
__global__ __launch_bounds__(256) void mfma_gemm(
    const __bf16* __restrict__ A0, const __bf16* __restrict__ A1,
    const __bf16* __restrict__ WT, const float* __restrict__ bias,
    float* __restrict__ Cf, __bf16* __restrict__ Cb, int K, int N,
    const float* __restrict__ aw, float* __restrict__ scp,
    const float* __restrict__ wgt) {
    constexpr int SMEMB = (FLAGS & 8) ? (128 * 129 * 4) : (2 * 128 * 64 * 2);
    __shared__ __attribute__((aligned(16))) char smem[SMEMB];
    __bf16* As = (__bf16*)smem;
    __bf16* Bs = As + 128 * 64;
    int lin = blockIdx.x + 4 * blockIdx.y;
    int nid = xcd_swz(lin, 4 * gridDim.y);
    int bx = nid & 3, by = nid >> 2;
    int t = threadIdx.x, w = t >> 6, l = t & 63;
    int r0 = by * 128, c0 = bx * 128;
    int lr = l & 15, lg = l >> 4;
    int wr = (w >> 1) * 64, wc = (w & 1) * 64;
    f32x4 acc[4][4] = {};
    for (int k0 = 0; k0 < K; k0 += 64) {
        #pragma unroll
        for (int i = 0; i < 4; ++i) {
            int row = (w * 4 + i) * 8 + (l >> 3);
            int c8 = l & 7;
            if constexpr (CONCAT == 2) {
                if (k0 < 256) {
                    gload_lds16(A0 + (size_t)(r0 + row) * 256 + k0 + c8 * 8,
                                As + (w * 4 + i) * 512);
                } else {
                    int kk2 = k0 - 256 + c8 * 8;
                    size_t gr = (size_t)(r0 + row);
                    bf16x8 xa = *(const bf16x8*)(A1 + gr * 512 + kk2);
                    bf16x8 ya = *(const bf16x8*)(A1 + ((size_t)ROWS + gr) * 512 + kk2);
                    float wv = wgt[gr];
                    bf16x8 mx;
                    #pragma unroll
                    for (int j = 0; j < 8; ++j)
                        mx[j] = (__bf16)(wv * (float)xa[j] + (1.f - wv) * (float)ya[j]);
                    *(bf16x8*)(As + (w * 4 + i) * 512 + l * 8) = mx;
                }
            } else {
                gload_lds16(A0 + (size_t)(r0 + row) * K + k0 + c8 * 8,
                            As + (w * 4 + i) * 512);
            }
            gload_lds16(WT + (size_t)(c0 + row) * K + k0 + c8 * 8,
                        Bs + (w * 4 + i) * 512);
        }
        asm volatile("s_waitcnt vmcnt(0)" ::: "memory");
        __syncthreads();
        #pragma unroll
        for (int ks = 0; ks < 2; ++ks) {
            bf16x8 af[4], bfr[4];
            #pragma unroll
            for (int mi = 0; mi < 4; ++mi)
                af[mi] = *(const bf16x8*)(As + (wr + mi * 16 + lr) * 64 + ks * 32 + lg * 8);
            #pragma unroll
            for (int ni = 0; ni < 4; ++ni)
                bfr[ni] = *(const bf16x8*)(Bs + (wc + ni * 16 + lr) * 64 + ks * 32 + lg * 8);
            #pragma unroll
            for (int mi = 0; mi < 4; ++mi)
                #pragma unroll
                for (int ni = 0; ni < 4; ++ni)
                    acc[mi][ni] = __builtin_amdgcn_mfma_f32_16x16x32_bf16(
                        af[mi], bfr[ni], acc[mi][ni], 0, 0, 0);
        }
        __syncthreads();
    }
    if constexpr ((FLAGS & 8) != 0) {
        float* tile = (float*)smem;
        #pragma unroll
        for (int mi = 0; mi < 4; ++mi)
            #pragma unroll
            for (int r = 0; r < 4; ++r) {
                int rrow = wr + mi * 16 + lg * 4 + r;
                #pragma unroll
                for (int ni = 0; ni < 4; ++ni) {
                    int ccol = wc + ni * 16 + lr;
                    float v = acc[mi][ni][r];
                    if (bias) v += bias[c0 + ccol];
                    if constexpr ((FLAGS & 1) != 0) v = fmaxf(v, 0.f);
                    tile[rrow * 129 + ccol] = v;
                }
            }
        __syncthreads();
        int cc = t >> 6, rr2 = t & 63;
        #pragma unroll
        for (int cs = 0; cs < 128; cs += 4) {
            #pragma unroll
            for (int h = 0; h < 2; ++h) {
                int row = r0 + rr2 + h * 64;
                int bb = row / NPT, ii = row - bb * NPT;
                Cf[((size_t)bb * 512 + (c0 + cc + cs)) * NPT + ii] =
                    tile[(rr2 + h * 64) * 129 + cc + cs];
            }
        }
    } else if constexpr ((FLAGS & 16) != 0) {
        int half = (r0 >= ROWS) ? 1 : 0;
        float ps[4][4] = {};
        #pragma unroll
        for (int mi = 0; mi < 4; ++mi)
            #pragma unroll
            for (int r = 0; r < 4; ++r) {
                int row = r0 + wr + mi * 16 + lg * 4 + r;
                #pragma unroll
                for (int ni = 0; ni < 4; ++ni) {
                    int col = c0 + wc + ni * 16 + lr;
                    float v = acc[mi][ni][r] + bias[col];
                    Cb[(size_t)row * N + col] = (__bf16)v;
                    ps[mi][r] = fmaf(v, aw[half * 512 + col], ps[mi][r]);
                }
            }
        #pragma unroll
        for (int m = 1; m <= 8; m <<= 1)
            #pragma unroll
            for (int mi = 0; mi < 4; ++mi)
                #pragma unroll
                for (int r = 0; r < 4; ++r)
                    ps[mi][r] += __shfl_xor(ps[mi][r], m, 64);
        if (lr == 0) {
            int slot = half * 8 + bx * 2 + (w & 1);
            #pragma unroll
            for (int mi = 0; mi < 4; ++mi)
                #pragma unroll
                for (int r = 0; r < 4; ++r) {
                    int sr = r0 - half * ROWS + wr + mi * 16 + lg * 4 + r;
                    scp[(size_t)slot * ROWS + sr] = ps[mi][r];
                }
        }
    } else {
        #pragma unroll
        for (int mi = 0; mi < 4; ++mi) {
            #pragma unroll
            for (int r = 0; r < 4; ++r) {
                int row = r0 + wr + mi * 16 + lg * 4 + r;
                #pragma unroll
                for (int ni = 0; ni < 4; ++ni) {
                    int col = c0 + wc + ni * 16 + lr;
                    float v = acc[mi][ni][r];
                    if (bias) v += bias[col];
                    if constexpr ((FLAGS & 1) != 0) v = fmaxf(v, 0.f);
                    if constexpr ((FLAGS & 4) != 0)
                        Cb[(size_t)row * N + col] = (__bf16)v;
                    else
                        Cf[(size_t)row * N + col] = v;
                }
            }
        }
    }
}

// ------- single-dispatch softmax: per-block partials + fence/atomic last-block combine -------
__global__ __launch_bounds__(256) void softmax_all(const float* __restrict__ scp,
        const float* __restrict__ ab, float* __restrict__ scores,
        float* __restrict__ mpart, float* __restrict__ spart,
        int* __restrict__ cnt, float* __restrict__ wgt) {
    __shared__ float red[256];
    __shared__ float MS[2];
    __shared__ bool islast;
    int t = threadIdx.x;
    int sr = blockIdx.x * 256 + t;              // 49*256 = ROWS exactly
    float s = ab[0];
    #pragma unroll
    for (int i = 0; i < 16; ++i) s += scp[(size_t)i * ROWS + sr];
    scores[sr] = s;
    red[t] = s; __syncthreads();
    for (int off = 128; off; off >>= 1) {
        if (t < off) red[t] = fmaxf(red[t], red[t + off]);
        __syncthreads();
    }
    float mb = red[0]; __syncthreads();
    red[t] = expf(s - mb); __syncthreads();
    for (int off = 128; off; off >>= 1) {
        if (t < off) red[t] += red[t + off];
        __syncthreads();
    }
    if (t == 0) {
        mpart[blockIdx.x] = mb;
        spart[blockIdx.x] = red[0];
        __threadfence();
        int old = atomicAdd(cnt, 1);
        islast = (old == 48);
    }
    __syncthreads();
    if (!islast) return;
    __threadfence();
    if (t == 0) {
        float M = mpart[0];
        for (int i = 1; i < 49; ++i) M = fmaxf(M, mpart[i]);
        float S = 0.f;
        for (int i = 0; i < 49; ++i) S += spart[i] * expf(mpart[i] - M);
        MS[0] = M; MS[1] = S;
        cnt[0] = 0;
    }
    __syncthreads();
    float M = MS[0], denom = MS[1];
    for (int i = t; i < ROWS; i += 256)
        wgt[i] = expf(scores[i] - M) / denom;
}

extern "C" void kernel_launch(void* const* d_in, const int* in_sizes, int n_in,
                              void* d_out, int out_size, void* d_ws, size_t ws_size,
                              hipStream_t stream) {
    (void)in_sizes; (void)n_in; (void)out_size; (void)ws_size;
    const float* x       = (const float*)d_in[0];
    const float* fc1_w   = (const float*)d_in[1];
    const float* fc1_b   = (const float*)d_in[2];
    const float* fc2_w   = (const float*)d_in[3];
    const float* fc2_b   = (const float*)d_in[4];
    const float* fce_w   = (const float*)d_in[5];
    const float* fce_b   = (const float*)d_in[6];
    const float* inout_w = (const float*)d_in[7];
    const float* inout_b = (const float*)d_in[8];
    const float* attn_w  = (const float*)d_in[9];
    const float* attn_b  = (const float*)d_in[10];
    const float* upd_w   = (const float*)d_in[11];
    const float* upd_b   = (const float*)d_in[12];
    const float* kp_w    = (const float*)d_in[13];
    const float* kp_b    = (const float*)d_in[14];
    const float* enc_w   = (const float*)d_in[15];
    const float* enc_b   = (const float*)d_in[16];
    const float* mu_w    = (const float*)d_in[17];
    const float* mu_b    = (const float*)d_in[18];
    const float* dec_w   = (const float*)d_in[19];
    const float* dec_b   = (const float*)d_in[20];
    float* out = (float*)d_out;

    char* base = (char*)d_ws;
    size_t o = 0;
    auto alloc = [&](size_t bytes) -> void* {
        void* p = base + o;
        o += (bytes + 255) & ~(size_t)255;
        return p;
    };
    float* qsp    = (float*)alloc((size_t)4 * 64 * 256 * 4);        //  0.26 MB
    float* degf   = (float*)alloc(ROWS * 4);
    float* scores = (float*)alloc(ROWS * 4);
    float* wgt    = (float*)alloc(ROWS * 4);
    int*   kint   = (int*)  alloc(ROWS * 4);
    float* KW1    = (float*)alloc(256 * 64 * 4);
    float* kb1    = (float*)alloc(64 * 4);
    float* KW2    = (float*)alloc(64 * 9 * 4);
    float* kb2    = (float*)alloc(9 * 4);
    float* bcomp  = (float*)alloc(512 * 4);
    float* scp    = (float*)alloc((size_t)16 * ROWS * 4);           //  0.80 MB
    float* mpart  = (float*)alloc(64 * 4);
    float* spart  = (float*)alloc(64 * 4);
    int*   smcnt  = (int*)  alloc(256);
    int*   nbr    = (int*)  alloc((size_t)128 * NPT * KNB * 4);     //  0.80 MB
    char*  regD   = (char*) alloc((size_t)ROWS * 512 * 2);          // 12.85 MB
    __bf16* XB    = (__bf16*)alloc((size_t)ROWS * 256 * 2);         //  6.42 MB
    __bf16* H1    = (__bf16*)alloc((size_t)2 * ROWS * 256 * 2);     // 12.85 MB
    __bf16* H2    = (__bf16*)alloc((size_t)2 * ROWS * 256 * 2);     // 12.85 MB
    char*  regAGG = (char*) alloc((size_t)2 * ROWS * 512 * 4);      // 51.38 MB
    __bf16* W1catT= (__bf16*)alloc((size_t)512 * 256 * 2);
    __bf16* W2catT= (__bf16*)alloc((size_t)512 * 256 * 2);
    __bf16* fcet  = (__bf16*)alloc((size_t)512 * 256 * 2);
    __bf16* updC  = (__bf16*)alloc((size_t)512 * 768 * 2);
    // --- aliases (stream-order safe) ---
    __bf16* P1buf = (__bf16*)regD;                 // stage-1 P, dead after combine1
    _Float16* XSPH = (_Float16*)regAGG;            // [0, 8.39MB), dead after gram
    _Float16* XSPL = XSPH + (size_t)64 * 256 * 256;// [8.39, 16.78MB)
    float* Dw     = (float*)(regAGG + (size_t)17 * 1024 * 1024);  // 21.2MB, dead after topk
    __bf16* P2buf = (__bf16*)regAGG;               // stage-2 P (25.7MB), after topk
    __bf16* AGGb  = (__bf16*)regAGG;               // fce output (bf16), 25.7 MB
    __bf16* XAGGb = AGGb;

    // ---- K1: trans_split+qs + full prep ----
    front_kernel<<<1766, 256, 0, stream>>>(x, XSPH, XSPL, XB, qsp,
                                           fc1_w, fc2_w, fce_w, upd_w,
                                           kp_w, kp_b, enc_w, enc_b,
                                           mu_w, mu_b, dec_w, dec_b,
                                           inout_w, inout_b, upd_b,
                                           W1catT, W2catT, fcet, updC,
                                           KW1, kb1, KW2, kb2, bcomp, smcnt);

    // ---- K2: gram 64x64 dbuf + XOR-swizzled LDS (dist -> HBM) + k-predictor ----
    gram_kint<<<2832, 256, 0, stream>>>(XSPH, XSPL, qsp, Dw, x,
                                        KW1, kb1, KW2, kb2, kint, degf);

    // ---- K3: topk + P1 projection GEMM ----
    topk_p1<<<784, 256, 0, stream>>>(Dw, nbr, XB, W1catT, P1buf);

    // ---- EdgeConv combine 1 ----
    combine_kernel<1, 1><<<2 * ROWS / 4, 256, 0, stream>>>(
        P1buf, nbr, kint, degf, fc1_b, H1);

    // ---- EdgeConv stage 2 ----
    mfma_gemm<4, 0><<<dim3(4, 196), 256, 0, stream>>>(
        H1, nullptr, W2catT, nullptr, nullptr, P2buf, 256, 512,
        nullptr, nullptr, nullptr);
    combine_kernel<2, 0><<<2 * ROWS / 4, 256, 0, stream>>>(
        P2buf, nbr, kint, degf, fc2_b, H2);

    // ---- fce (bf16 out + fused attention-score partials) ----
    mfma_gemm<20, 0><<<dim3(4, 196), 256, 0, stream>>>(
        H2, nullptr, fcet, fce_b, nullptr, AGGb, 256, 512,
        attn_w, scp, nullptr);

    // ---- softmax (single dispatch, deterministic last-block combine) ----
    softmax_all<<<49, 256, 0, stream>>>(scp, attn_b, scores, mpart, spart,
                                        smcnt, wgt);

    // ---- final upd GEMM: inline wgt-mix A-staging, composed inout, transposed out ----
    mfma_gemm<9, 2><<<dim3(4, 98), 256, 0, stream>>>(
        XB, XAGGb, updC, bcomp, out, nullptr, 768, 512,
        nullptr, nullptr, wgt);
}